// Round 1
// baseline (486.589 us; speedup 1.0000x reference)
//
#include <hip/hip_runtime.h>

// MetapathGATConv fused kernel for MI355X (gfx950).
// N=16384 nodes, R=8 relations, D=256, H=4, C=64 (HC=256).
// One WG = NB=4 nodes = 32 M-rows. bf16 MFMA 16x16x32 for all GEMMs.

#define NNODES 16384
#define NB 4
#define MR 32              // rows per WG = NB*8
#define XLR_S 520          // layer-0 xl|xr LDS row stride (shorts): 512+8 pad -> +4 banks/row
#define XL1_S 264          // layer-1 xl1/xrs LDS row stride (shorts): 256+8 pad
#define XRS_OFF (32 * XL1_S)

typedef __bf16 bf16x8 __attribute__((ext_vector_type(8)));
typedef float f32x4 __attribute__((ext_vector_type(4)));
typedef unsigned short u16x8 __attribute__((ext_vector_type(8)));
typedef unsigned short u16x4 __attribute__((ext_vector_type(4)));

__device__ __forceinline__ unsigned short f2bf(float x) {
    unsigned u = __float_as_uint(x);
    u += 0x7FFFu + ((u >> 16) & 1u);            // RNE
    return (unsigned short)(u >> 16);
}
__device__ __forceinline__ float b2f(unsigned short s) {
    return __uint_as_float(((unsigned)s) << 16);
}

// Transpose + cast weights to bf16 W^T[n][k] so MFMA B-fragments are contiguous 16B.
// wt layout: rows 0-255: Wl0^T | 256-511: Wr0^T | 512-767: Wl1^T | 768-1023: Wr1^T.
__global__ void prep_weights(const float* __restrict__ Wl0, const float* __restrict__ Wr0,
                             const float* __restrict__ Wl1, const float* __restrict__ Wr1,
                             unsigned short* __restrict__ wt) {
    const int row = blockIdx.x;   // output row n (0..1023)
    const int d   = threadIdx.x;  // k (0..255)
    const float* src; int n;
    if (row < 256)      { src = Wl0; n = row; }
    else if (row < 512) { src = Wr0; n = row - 256; }
    else if (row < 768) { src = Wl1; n = row - 512; }
    else                { src = Wr1; n = row - 768; }
    wt[row * 256 + d] = f2bf(src[d * 256 + n]);
}

__launch_bounds__(256, 2)
__global__ void gat_fused(const float* __restrict__ x,
                          const float* __restrict__ bl0, const float* __restrict__ br0,
                          const float* __restrict__ att0, const float* __restrict__ bias0,
                          const float* __restrict__ bl1, const float* __restrict__ br1,
                          const float* __restrict__ att1, const float* __restrict__ bias1,
                          const unsigned short* __restrict__ wt,
                          float* __restrict__ out) {
    __shared__ unsigned short hA[MR * 256];       // 16 KB: bf16 A-tile (relu(x), later h1), XOR-swizzled k-chunks
    __shared__ unsigned short xlr[MR * XLR_S];    // 32.5 KB: xl0|xr0 (stride 520); reused as xl1+xrs (stride 264)
    __shared__ unsigned short selfA[16 * 256];    // 8 KB: compacted self rows for xr GEMM (swizzled)
    __shared__ float attbuf[1024];                // 4 KB: alpha0 / logits1 / alpha1

    const int tid  = threadIdx.x;
    const int bg   = blockIdx.x;
    const int lane = tid & 63;
    const int wv   = tid >> 6;
    const int lr   = lane & 15;
    const int lq   = lane >> 4;

    // ---------------- P0: hA = bf16(relu(x)) ----------------
    {
        const float4* src = (const float4*)(x + (size_t)bg * (MR * 256));
        #pragma unroll
        for (int it = 0; it < 4; ++it) {
            int g   = it * 256 + tid;       // 8-elem chunk id, 0..1023
            int row = g >> 5;
            int c   = g & 31;
            int cs  = c ^ (row & 7);        // bank swizzle
            float4 v0 = src[2 * g];
            float4 v1 = src[2 * g + 1];
            u16x8 s;
            s[0] = f2bf(fmaxf(v0.x, 0.f)); s[1] = f2bf(fmaxf(v0.y, 0.f));
            s[2] = f2bf(fmaxf(v0.z, 0.f)); s[3] = f2bf(fmaxf(v0.w, 0.f));
            s[4] = f2bf(fmaxf(v1.x, 0.f)); s[5] = f2bf(fmaxf(v1.y, 0.f));
            s[6] = f2bf(fmaxf(v1.z, 0.f)); s[7] = f2bf(fmaxf(v1.w, 0.f));
            *(u16x8*)&hA[row * 256 + cs * 8] = s;
        }
    }
    __syncthreads();

    // ---------------- P1: GEMM0 -> xl0|xr0 (C[32][512]) ----------------
    // wave wv owns 128 N-cols; A: 2 M-tiles; K: 8 steps of 32.
    {
        f32x4 acc[2][8];
        #pragma unroll
        for (int m = 0; m < 2; ++m)
            #pragma unroll
            for (int n = 0; n < 8; ++n)
                acc[m][n] = f32x4{0.f, 0.f, 0.f, 0.f};
        #pragma unroll
        for (int kt = 0; kt < 8; ++kt) {
            bf16x8 a[2], b[8];
            const int csA = ((kt * 4 + lq) ^ (lr & 7)) * 8;
            #pragma unroll
            for (int m = 0; m < 2; ++m)
                a[m] = *(const bf16x8*)&hA[(m * 16 + lr) * 256 + csA];
            const int koff = kt * 32 + lq * 8;
            #pragma unroll
            for (int n = 0; n < 8; ++n)
                b[n] = *(const bf16x8*)&wt[(wv * 128 + n * 16 + lr) * 256 + koff];
            #pragma unroll
            for (int m = 0; m < 2; ++m)
                #pragma unroll
                for (int n = 0; n < 8; ++n)
                    acc[m][n] = __builtin_amdgcn_mfma_f32_16x16x32_bf16(a[m], b[n], acc[m][n], 0, 0, 0);
        }
        #pragma unroll
        for (int n = 0; n < 8; ++n) {
            const int col = wv * 128 + n * 16 + lr;     // 0..511 (xl | xr)
            const float bias = (col < 256) ? bl0[col] : br0[col - 256];
            #pragma unroll
            for (int m = 0; m < 2; ++m)
                #pragma unroll
                for (int r = 0; r < 4; ++r) {
                    const int row = m * 16 + lq * 4 + r;
                    xlr[row * XLR_S + col] = f2bf(acc[m][n][r] + bias);
                }
        }
    }
    __syncthreads();

    // ---------------- P2: layer-0 logits + softmax over j ----------------
    // thread = (n, i, h, jh): computes 4 j-logits, pairs via shfl_xor(1).
    {
        const int n  = tid >> 6;
        const int i  = (tid >> 3) & 7;
        const int h  = (tid >> 1) & 3;
        const int jh = tid & 1;
        const int rot = lane & 7;   // per-lane chunk rotation to spread LDS banks
        float xr[8][8];
        const int xrb = (n * 8 + i) * XLR_S + 256 + h * 64;
        #pragma unroll
        for (int c0 = 0; c0 < 8; ++c0) {
            const int cc = (c0 + rot) & 7;
            u16x8 v = *(const u16x8*)&xlr[xrb + cc * 8];
            #pragma unroll
            for (int e = 0; e < 8; ++e) xr[c0][e] = b2f(v[e]);
        }
        float lg[4];
        #pragma unroll
        for (int jj = 0; jj < 4; ++jj) {
            const int j = jh * 4 + jj;
            const int xlb = (n * 8 + j) * XLR_S + h * 64;
            float s = 0.f;
            #pragma unroll
            for (int c0 = 0; c0 < 8; ++c0) {
                const int cc = (c0 + rot) & 7;
                u16x8 v = *(const u16x8*)&xlr[xlb + cc * 8];
                #pragma unroll
                for (int e = 0; e < 8; ++e) {
                    float t = xr[c0][e] + b2f(v[e]);
                    t = fmaxf(t, 0.2f * t);               // leaky_relu(0.2)
                    s = fmaf(t, att0[h * 64 + cc * 8 + e], s);
                }
            }
            lg[jj] = s;
        }
        float mx = fmaxf(fmaxf(lg[0], lg[1]), fmaxf(lg[2], lg[3]));
        mx = fmaxf(mx, __shfl_xor(mx, 1));
        float ex[4], ssum = 0.f;
        #pragma unroll
        for (int jj = 0; jj < 4; ++jj) { ex[jj] = __expf(lg[jj] - mx); ssum += ex[jj]; }
        const float tot = ssum + __shfl_xor(ssum, 1);
        const float inv = 1.f / tot;
        #pragma unroll
        for (int jj = 0; jj < 4; ++jj)
            attbuf[((n * 8 + i) * 4 + h) * 8 + jh * 4 + jj] = ex[jj] * inv;
    }
    __syncthreads();

    // ---------------- P3: h1 = relu(alpha @ xl0 + bias0) -> hA ----------------
    // thread = (row, h, half): 32 output cols.
    {
        const int row  = tid >> 3;
        const int sub  = tid & 7;
        const int h    = sub >> 1;
        const int half = sub & 1;
        const int c0   = h * 64 + half * 32;
        const int nn   = row >> 3;
        float alpha[8];
        #pragma unroll
        for (int j = 0; j < 8; ++j) alpha[j] = attbuf[(row * 4 + h) * 8 + j];
        float o[32];
        #pragma unroll
        for (int c = 0; c < 32; ++c) o[c] = 0.f;
        #pragma unroll
        for (int j = 0; j < 8; ++j) {
            const int xlb = (nn * 8 + j) * XLR_S + c0;
            #pragma unroll
            for (int cc = 0; cc < 4; ++cc) {
                u16x8 v = *(const u16x8*)&xlr[xlb + cc * 8];
                #pragma unroll
                for (int e = 0; e < 8; ++e)
                    o[cc * 8 + e] = fmaf(b2f(v[e]), alpha[j], o[cc * 8 + e]);
            }
        }
        #pragma unroll
        for (int cc = 0; cc < 4; ++cc) {
            u16x8 s;
            #pragma unroll
            for (int e = 0; e < 8; ++e) {
                float v = o[cc * 8 + e] + bias0[c0 + cc * 8 + e];
                s[e] = f2bf(fmaxf(v, 0.f));
            }
            const int c  = (c0 >> 3) + cc;
            const int cs = c ^ (row & 7);
            *(u16x8*)&hA[row * 256 + cs * 8] = s;
        }
    }
    __syncthreads();

    // ---------------- P4: compact self rows (r=7) into selfA[16][256] ----------------
    {
        const int row = tid >> 4;          // 0..15 (only 0..NB-1 real)
        const int cp  = (tid & 15) * 2;
        #pragma unroll
        for (int k = 0; k < 2; ++k) {
            const int c = cp + k;
            u16x8 v = u16x8{0, 0, 0, 0, 0, 0, 0, 0};
            if (row < NB)
                v = *(const u16x8*)&hA[(row * 8 + 7) * 256 + (c ^ 7) * 8];  // src row&7 == 7
            *(u16x8*)&selfA[row * 256 + (c ^ (row & 7)) * 8] = v;
        }
    }
    __syncthreads();

    // ---------------- P5: GEMM1: xl1 = h1@Wl1+bl1 ; xrs = self@Wr1+br1 ----------------
    {
        f32x4 accl[2][4], accr[4];
        #pragma unroll
        for (int m = 0; m < 2; ++m)
            #pragma unroll
            for (int n = 0; n < 4; ++n)
                accl[m][n] = f32x4{0.f, 0.f, 0.f, 0.f};
        #pragma unroll
        for (int n = 0; n < 4; ++n) accr[n] = f32x4{0.f, 0.f, 0.f, 0.f};
        const unsigned short* W1l = wt + 512 * 256;
        const unsigned short* W1r = wt + 768 * 256;
        #pragma unroll
        for (int kt = 0; kt < 8; ++kt) {
            const int koff = kt * 32 + lq * 8;
            const int csA  = ((kt * 4 + lq) ^ (lr & 7)) * 8;
            bf16x8 a[2], as, bl[4], br[4];
            #pragma unroll
            for (int m = 0; m < 2; ++m)
                a[m] = *(const bf16x8*)&hA[(m * 16 + lr) * 256 + csA];
            as = *(const bf16x8*)&selfA[lr * 256 + csA];
            #pragma unroll
            for (int n = 0; n < 4; ++n) {
                bl[n] = *(const bf16x8*)&W1l[(wv * 64 + n * 16 + lr) * 256 + koff];
                br[n] = *(const bf16x8*)&W1r[(wv * 64 + n * 16 + lr) * 256 + koff];
            }
            #pragma unroll
            for (int m = 0; m < 2; ++m)
                #pragma unroll
                for (int n = 0; n < 4; ++n)
                    accl[m][n] = __builtin_amdgcn_mfma_f32_16x16x32_bf16(a[m], bl[n], accl[m][n], 0, 0, 0);
            #pragma unroll
            for (int n = 0; n < 4; ++n)
                accr[n] = __builtin_amdgcn_mfma_f32_16x16x32_bf16(as, br[n], accr[n], 0, 0, 0);
        }
        #pragma unroll
        for (int n = 0; n < 4; ++n) {
            const int col = wv * 64 + n * 16 + lr;
            const float b1 = bl1[col], b2 = br1[col];
            #pragma unroll
            for (int m = 0; m < 2; ++m)
                #pragma unroll
                for (int r = 0; r < 4; ++r)
                    xlr[(m * 16 + lq * 4 + r) * XL1_S + col] = f2bf(accl[m][n][r] + b1);
            #pragma unroll
            for (int r = 0; r < 4; ++r)
                xlr[XRS_OFF + (lq * 4 + r) * XL1_S + col] = f2bf(accr[n][r] + b2);
        }
    }
    __syncthreads();

    // ---------------- P6: layer-1 logits, softmax over r -> betas ----------------
    {
        const int n  = tid >> 5;
        const int rr = (tid >> 2) & 7;
        const int h  = tid & 3;
        float lg = 0.f;
        if (tid < 128) {
            const int xrb = XRS_OFF + n * XL1_S + h * 64;
            const int xlb = (n * 8 + rr) * XL1_S + h * 64;
            #pragma unroll
            for (int cc = 0; cc < 8; ++cc) {
                u16x8 vr = *(const u16x8*)&xlr[xrb + cc * 8];
                u16x8 vl = *(const u16x8*)&xlr[xlb + cc * 8];
                #pragma unroll
                for (int e = 0; e < 8; ++e) {
                    float t = b2f(vr[e]) + b2f(vl[e]);
                    t = fmaxf(t, 0.2f * t);
                    lg = fmaf(t, att1[h * 64 + cc * 8 + e], lg);
                }
            }
            attbuf[tid] = lg;
        }
        __syncthreads();
        if (tid < 128) {
            float l[8], M = -1e30f;
            #pragma unroll
            for (int j = 0; j < 8; ++j) {
                l[j] = attbuf[n * 32 + j * 4 + h];
                M = fmaxf(M, l[j]);
            }
            float S = 0.f;
            #pragma unroll
            for (int j = 0; j < 8; ++j) S += __expf(l[j] - M);
            const float a = __expf(lg - M) / S;
            attbuf[256 + tid] = a;
            out[(size_t)NNODES * 256 + (size_t)(bg * NB + n) * 32 + rr * 4 + h] = a;  // betas
        }
        __syncthreads();
    }

    // ---------------- P7: out = relu(alpha1 @ xl1 + bias1) ----------------
    {
        const int n  = tid >> 6;
        const int q  = tid & 63;
        const int c0 = q * 4;
        const int h  = q >> 4;
        float o0 = 0.f, o1 = 0.f, o2 = 0.f, o3 = 0.f;
        #pragma unroll
        for (int r = 0; r < 8; ++r) {
            const float a = attbuf[256 + n * 32 + r * 4 + h];
            u16x4 v = *(const u16x4*)&xlr[(n * 8 + r) * XL1_S + c0];
            o0 = fmaf(b2f(v[0]), a, o0);
            o1 = fmaf(b2f(v[1]), a, o1);
            o2 = fmaf(b2f(v[2]), a, o2);
            o3 = fmaf(b2f(v[3]), a, o3);
        }
        float4 res;
        res.x = fmaxf(o0 + bias1[c0 + 0], 0.f);
        res.y = fmaxf(o1 + bias1[c0 + 1], 0.f);
        res.z = fmaxf(o2 + bias1[c0 + 2], 0.f);
        res.w = fmaxf(o3 + bias1[c0 + 3], 0.f);
        *(float4*)&out[(size_t)(bg * NB + n) * 256 + c0] = res;
    }
}

extern "C" void kernel_launch(void* const* d_in, const int* in_sizes, int n_in,
                              void* d_out, int out_size, void* d_ws, size_t ws_size,
                              hipStream_t stream) {
    const float* x     = (const float*)d_in[0];
    const float* Wl0   = (const float*)d_in[1];
    const float* bl0   = (const float*)d_in[2];
    const float* Wr0   = (const float*)d_in[3];
    const float* br0   = (const float*)d_in[4];
    const float* att0  = (const float*)d_in[5];
    const float* bias0 = (const float*)d_in[6];
    const float* Wl1   = (const float*)d_in[7];
    const float* bl1   = (const float*)d_in[8];
    const float* Wr1   = (const float*)d_in[9];
    const float* br1   = (const float*)d_in[10];
    const float* att1  = (const float*)d_in[11];
    const float* bias1 = (const float*)d_in[12];
    unsigned short* wt = (unsigned short*)d_ws;   // needs 512 KB
    float* out = (float*)d_out;

    prep_weights<<<1024, 256, 0, stream>>>(Wl0, Wr0, Wl1, Wr1, wt);
    gat_fused<<<NNODES / NB, 256, 0, stream>>>(x, bl0, br0, att0, bias0,
                                               bl1, br1, att1, bias1, wt, out);
}

// Round 2
// 465.708 us; speedup vs baseline: 1.0448x; 1.0448x over previous
//
#include <hip/hip_runtime.h>

// MetapathGATConv fused kernel for MI355X (gfx950) — R1.
// N=16384 nodes, R=8 relations, D=256, H=4, C=64 (HC=256).
// One WG = NB=4 nodes = 32 M-rows. bf16 MFMA 16x16x32 for all GEMMs.
// R1: LDS 62KB -> 36KB (4 WG/CU): two 16KB XOR-swizzled bf16 buffers with
// phase-based reuse, selfA dropped (lane%4 self-row trick), coalesced
// LDS-transpose weight prep.

#define NNODES 16384
#define NB 4
#define MR 32              // rows per WG = NB*8

typedef __bf16 bf16x8 __attribute__((ext_vector_type(8)));
typedef __bf16 bf16x4 __attribute__((ext_vector_type(4)));
typedef float f32x4 __attribute__((ext_vector_type(4)));
typedef float f32x8 __attribute__((ext_vector_type(8)));

// swizzled chunk address: buffers are [32 rows][32 chunks of 8 bf16],
// chunk index XORed with (row&7) so column-strided accesses spread banks.
__device__ __forceinline__ int swz(int row, int chunk) {
    return row * 256 + ((chunk ^ (row & 7)) << 3);
}

// ---------------- weight prep: transpose+cast to bf16 W^T[n][k] ----------------
// wt rows 0-255: Wl0^T | 256-511: Wr0^T | 512-767: Wl1^T | 768-1023: Wr1^T.
// grid: 16 blocks = 4 matrices x 4 k-tiles(64); coalesced loads, LDS transpose.
__global__ void prep_weights(const float* __restrict__ Wl0, const float* __restrict__ Wr0,
                             const float* __restrict__ Wl1, const float* __restrict__ Wr1,
                             __bf16* __restrict__ wt) {
    __shared__ float tile[64 * 68];   // 64x64 + pad 4
    const int t  = threadIdx.x;
    const int m  = blockIdx.x >> 2;
    const int kt = blockIdx.x & 3;
    const float* src = (m == 0 ? Wl0 : m == 1 ? Wr0 : m == 2 ? Wl1 : Wr1) + kt * 64 * 256;
    for (int nt = 0; nt < 4; ++nt) {
        #pragma unroll
        for (int i = 0; i < 4; ++i) {
            const int idx = i * 256 + t;     // float4 id 0..1023
            const int kk  = idx >> 4;
            const int nn  = (idx & 15) * 4;
            const float4 v = *(const float4*)&src[kk * 256 + nt * 64 + nn];
            tile[kk * 68 + nn + 0] = v.x;
            tile[kk * 68 + nn + 1] = v.y;
            tile[kk * 68 + nn + 2] = v.z;
            tile[kk * 68 + nn + 3] = v.w;
        }
        __syncthreads();
        const int n  = t >> 2;
        const int ks = (t & 3) * 16;
        bf16x8 o0, o1;
        #pragma unroll
        for (int e = 0; e < 8; ++e) o0[e] = (__bf16)tile[(ks + e) * 68 + n];
        #pragma unroll
        for (int e = 0; e < 8; ++e) o1[e] = (__bf16)tile[(ks + 8 + e) * 68 + n];
        __bf16* dst = &wt[(size_t)(m * 256 + nt * 64 + n) * 256 + kt * 64 + ks];
        *(bf16x8*)dst = o0;
        *(bf16x8*)(dst + 8) = o1;
        __syncthreads();
    }
}

__launch_bounds__(256, 4)
__global__ void gat_fused(const float* __restrict__ x,
                          const float* __restrict__ bl0, const float* __restrict__ br0,
                          const float* __restrict__ att0, const float* __restrict__ bias0,
                          const float* __restrict__ bl1, const float* __restrict__ br1,
                          const float* __restrict__ att1, const float* __restrict__ bias1,
                          const __bf16* __restrict__ wt,
                          float* __restrict__ out) {
    __shared__ __bf16 bufA[MR * 256];   // 16 KB: relu(x) -> xr0 -> h1
    __shared__ __bf16 bufB[MR * 256];   // 16 KB: xl0 -> xl1
    __shared__ float attbuf[1024];      // 4 KB: alpha0; later xrs(bf16) | logits1 | alpha1

    const int tid  = threadIdx.x;
    const int bg   = blockIdx.x;
    const int lane = tid & 63;
    const int wv   = tid >> 6;
    const int lr   = lane & 15;
    const int lq   = lane >> 4;

    // ---------------- P0: bufA = bf16(relu(x)), swizzled ----------------
    {
        const float4* src = (const float4*)(x + (size_t)bg * (MR * 256));
        #pragma unroll
        for (int it = 0; it < 4; ++it) {
            const int g   = it * 256 + tid;   // 8-elem chunk id, 0..1023
            const int row = g >> 5;
            const int c   = g & 31;
            const float4 v0 = src[2 * g];
            const float4 v1 = src[2 * g + 1];
            bf16x8 s;
            s[0] = (__bf16)fmaxf(v0.x, 0.f); s[1] = (__bf16)fmaxf(v0.y, 0.f);
            s[2] = (__bf16)fmaxf(v0.z, 0.f); s[3] = (__bf16)fmaxf(v0.w, 0.f);
            s[4] = (__bf16)fmaxf(v1.x, 0.f); s[5] = (__bf16)fmaxf(v1.y, 0.f);
            s[6] = (__bf16)fmaxf(v1.z, 0.f); s[7] = (__bf16)fmaxf(v1.w, 0.f);
            *(bf16x8*)&bufA[swz(row, c)] = s;
        }
    }
    __syncthreads();

    // ---------------- P1: GEMM0 C[32][512] = relu(x) @ [Wl0|Wr0] ----------------
    // wave wv owns 128 N-cols; waves 0,1 -> xl (bufB), waves 2,3 -> xr (bufA).
    {
        f32x4 acc[2][8];
        #pragma unroll
        for (int m = 0; m < 2; ++m)
            #pragma unroll
            for (int n = 0; n < 8; ++n)
                acc[m][n] = f32x4{0.f, 0.f, 0.f, 0.f};
        #pragma unroll
        for (int kt = 0; kt < 8; ++kt) {
            bf16x8 a[2], b[8];
            #pragma unroll
            for (int m = 0; m < 2; ++m)
                a[m] = *(const bf16x8*)&bufA[swz(m * 16 + lr, kt * 4 + lq)];
            const int koff = kt * 32 + lq * 8;
            #pragma unroll
            for (int n = 0; n < 8; ++n)
                b[n] = *(const bf16x8*)&wt[(size_t)(wv * 128 + n * 16 + lr) * 256 + koff];
            #pragma unroll
            for (int m = 0; m < 2; ++m)
                #pragma unroll
                for (int n = 0; n < 8; ++n)
                    acc[m][n] = __builtin_amdgcn_mfma_f32_16x16x32_bf16(a[m], b[n], acc[m][n], 0, 0, 0);
        }
        __syncthreads();   // all A-reads of bufA done before xr overwrites it
        __bf16* dstbuf = (wv < 2) ? bufB : bufA;
        const float* bv = (wv < 2) ? bl0 : br0;
        #pragma unroll
        for (int n = 0; n < 8; ++n) {
            const int cl   = (wv & 1) * 128 + n * 16 + lr;   // 0..255 within dst buffer
            const float bias = bv[cl];
            const int ch   = cl >> 3, ce = cl & 7;
            #pragma unroll
            for (int m = 0; m < 2; ++m)
                #pragma unroll
                for (int r = 0; r < 4; ++r) {
                    const int row = m * 16 + lq * 4 + r;
                    dstbuf[swz(row, ch) + ce] = (__bf16)(acc[m][n][r] + bias);
                }
        }
    }
    __syncthreads();

    // ---------------- P2: layer-0 logits + softmax over j -> alpha0 ----------------
    // thread = (n=wave, i, h, jh): 4 j-logits each, pair-reduce via shfl_xor(1).
    {
        const int n  = tid >> 6;
        const int i  = (tid >> 3) & 7;
        const int h  = (tid >> 1) & 3;
        const int jh = tid & 1;
        const int rot = lane & 7;
        const int rowR = n * 8 + i;
        float lg[4] = {0.f, 0.f, 0.f, 0.f};
        #pragma unroll
        for (int c0 = 0; c0 < 8; ++c0) {
            const int cc = (c0 + rot) & 7;
            const bf16x8 vr = *(const bf16x8*)&bufA[swz(rowR, h * 8 + cc)];
            const f32x8 xr = __builtin_convertvector(vr, f32x8);
            const float4 a0 = *(const float4*)&att0[h * 64 + cc * 8];
            const float4 a1 = *(const float4*)&att0[h * 64 + cc * 8 + 4];
            const float av[8] = {a0.x, a0.y, a0.z, a0.w, a1.x, a1.y, a1.z, a1.w};
            #pragma unroll
            for (int jj = 0; jj < 4; ++jj) {
                const int rowL = n * 8 + jh * 4 + jj;
                const bf16x8 vl = *(const bf16x8*)&bufB[swz(rowL, h * 8 + cc)];
                const f32x8 xl = __builtin_convertvector(vl, f32x8);
                #pragma unroll
                for (int e = 0; e < 8; ++e) {
                    float t = xr[e] + xl[e];
                    t = fmaxf(t, 0.2f * t);               // leaky_relu(0.2)
                    lg[jj] = fmaf(t, av[e], lg[jj]);
                }
            }
        }
        float mx = fmaxf(fmaxf(lg[0], lg[1]), fmaxf(lg[2], lg[3]));
        mx = fmaxf(mx, __shfl_xor(mx, 1));
        float ex[4], ssum = 0.f;
        #pragma unroll
        for (int jj = 0; jj < 4; ++jj) { ex[jj] = __expf(lg[jj] - mx); ssum += ex[jj]; }
        const float tot = ssum + __shfl_xor(ssum, 1);
        const float inv = 1.f / tot;
        #pragma unroll
        for (int jj = 0; jj < 4; ++jj)
            attbuf[((n * 8 + i) * 4 + h) * 8 + jh * 4 + jj] = ex[jj] * inv;
    }
    __syncthreads();

    // ---------------- P3: h1 = relu(alpha0 @ xl0 + bias0) -> bufA ----------------
    // thread = (row, h, half): 32 output cols.
    {
        const int row  = tid >> 3;
        const int sub  = tid & 7;
        const int h    = sub >> 1;
        const int half = sub & 1;
        const int cb   = h * 8 + half * 4;   // base chunk (of 4)
        const int nn   = row >> 3;
        float alpha[8];
        #pragma unroll
        for (int j = 0; j < 8; ++j) alpha[j] = attbuf[(row * 4 + h) * 8 + j];
        float o[32];
        #pragma unroll
        for (int c = 0; c < 32; ++c) o[c] = 0.f;
        #pragma unroll
        for (int j = 0; j < 8; ++j) {
            const int rowj = nn * 8 + j;
            #pragma unroll
            for (int cc = 0; cc < 4; ++cc) {
                const bf16x8 v = *(const bf16x8*)&bufB[swz(rowj, cb + cc)];
                const f32x8 f = __builtin_convertvector(v, f32x8);
                #pragma unroll
                for (int e = 0; e < 8; ++e)
                    o[cc * 8 + e] = fmaf(f[e], alpha[j], o[cc * 8 + e]);
            }
        }
        #pragma unroll
        for (int cc = 0; cc < 4; ++cc) {
            bf16x8 s;
            #pragma unroll
            for (int e = 0; e < 8; ++e) {
                const float v = o[cc * 8 + e] + bias0[(cb + cc) * 8 + e];
                s[e] = (__bf16)fmaxf(v, 0.f);
            }
            *(bf16x8*)&bufA[swz(row, cb + cc)] = s;
        }
    }
    __syncthreads();

    // ---------------- P5: GEMM1: xl1 = h1@Wl1+bl1 -> bufB ; xrs = self@Wr1+br1 ----------------
    {
        f32x4 accl[2][4], accr[4];
        #pragma unroll
        for (int m = 0; m < 2; ++m)
            #pragma unroll
            for (int n = 0; n < 4; ++n)
                accl[m][n] = f32x4{0.f, 0.f, 0.f, 0.f};
        #pragma unroll
        for (int n = 0; n < 4; ++n) accr[n] = f32x4{0.f, 0.f, 0.f, 0.f};
        const __bf16* W1l = wt + 512 * 256;
        const __bf16* W1r = wt + 768 * 256;
        const int rowS = (lr & 3) * 8 + 7;    // self row of node (lr&3); rows>=4 of D are garbage, never read
        #pragma unroll
        for (int kt = 0; kt < 8; ++kt) {
            const int koff = kt * 32 + lq * 8;
            bf16x8 a[2], as, bl[4], br[4];
            #pragma unroll
            for (int m = 0; m < 2; ++m)
                a[m] = *(const bf16x8*)&bufA[swz(m * 16 + lr, kt * 4 + lq)];
            as = *(const bf16x8*)&bufA[swz(rowS, kt * 4 + lq)];
            #pragma unroll
            for (int n = 0; n < 4; ++n) {
                bl[n] = *(const bf16x8*)&W1l[(size_t)(wv * 64 + n * 16 + lr) * 256 + koff];
                br[n] = *(const bf16x8*)&W1r[(size_t)(wv * 64 + n * 16 + lr) * 256 + koff];
            }
            #pragma unroll
            for (int m = 0; m < 2; ++m)
                #pragma unroll
                for (int n = 0; n < 4; ++n)
                    accl[m][n] = __builtin_amdgcn_mfma_f32_16x16x32_bf16(a[m], bl[n], accl[m][n], 0, 0, 0);
            #pragma unroll
            for (int n = 0; n < 4; ++n)
                accr[n] = __builtin_amdgcn_mfma_f32_16x16x32_bf16(as, br[n], accr[n], 0, 0, 0);
        }
        __syncthreads();   // bufB (xl0) reads in P3 are done; safe to overwrite
        __bf16* xrs = (__bf16*)attbuf;   // alpha0 dead; 4x256 bf16 = 2 KB
        #pragma unroll
        for (int n = 0; n < 4; ++n) {
            const int col = wv * 64 + n * 16 + lr;
            const float b1 = bl1[col], b2 = br1[col];
            const int ch = col >> 3, ce = col & 7;
            #pragma unroll
            for (int m = 0; m < 2; ++m)
                #pragma unroll
                for (int r = 0; r < 4; ++r) {
                    const int row = m * 16 + lq * 4 + r;
                    bufB[swz(row, ch) + ce] = (__bf16)(accl[m][n][r] + b1);
                }
            if (lq == 0) {
                #pragma unroll
                for (int r = 0; r < 4; ++r)     // D rows 0..3 = nodes 0..3
                    xrs[r * 256 + col] = (__bf16)(accr[n][r] + b2);
            }
        }
    }
    __syncthreads();

    // ---------------- P6: layer-1 logits, softmax over r -> betas + alpha1 ----------------
    {
        const int n  = tid >> 5;
        const int rr = (tid >> 2) & 7;
        const int h  = tid & 3;
        const __bf16* xrs = (const __bf16*)attbuf;
        float lg = 0.f;
        if (tid < 128) {
            const int rowj = n * 8 + rr;
            #pragma unroll
            for (int cc = 0; cc < 8; ++cc) {
                const bf16x8 vr = *(const bf16x8*)&xrs[n * 256 + h * 64 + cc * 8];
                const bf16x8 vl = *(const bf16x8*)&bufB[swz(rowj, h * 8 + cc)];
                const float4 a0 = *(const float4*)&att1[h * 64 + cc * 8];
                const float4 a1 = *(const float4*)&att1[h * 64 + cc * 8 + 4];
                const float av[8] = {a0.x, a0.y, a0.z, a0.w, a1.x, a1.y, a1.z, a1.w};
                #pragma unroll
                for (int e = 0; e < 8; ++e) {
                    float t = (float)vr[e] + (float)vl[e];
                    t = fmaxf(t, 0.2f * t);
                    lg = fmaf(t, av[e], lg);
                }
            }
            attbuf[512 + tid] = lg;
        }
        __syncthreads();
        if (tid < 128) {
            float M = -1e30f;
            float l[8];
            #pragma unroll
            for (int j = 0; j < 8; ++j) {
                l[j] = attbuf[512 + n * 32 + j * 4 + h];
                M = fmaxf(M, l[j]);
            }
            float S = 0.f;
            #pragma unroll
            for (int j = 0; j < 8; ++j) S += __expf(l[j] - M);
            const float a = __expf(lg - M) / S;
            attbuf[768 + tid] = a;
            out[(size_t)NNODES * 256 + (size_t)(bg * NB + n) * 32 + rr * 4 + h] = a;  // betas
        }
    }
    __syncthreads();

    // ---------------- P7: out = relu(alpha1 @ xl1 + bias1) ----------------
    {
        const int n  = tid >> 6;
        const int q  = tid & 63;
        const int c0 = q * 4;
        const int h  = q >> 4;
        float o0 = 0.f, o1 = 0.f, o2 = 0.f, o3 = 0.f;
        #pragma unroll
        for (int r = 0; r < 8; ++r) {
            const float a = attbuf[768 + n * 32 + r * 4 + h];
            const int rowj = n * 8 + r;
            const bf16x4 v = *(const bf16x4*)&bufB[swz(rowj, q >> 1) + (q & 1) * 4];
            o0 = fmaf((float)v[0], a, o0);
            o1 = fmaf((float)v[1], a, o1);
            o2 = fmaf((float)v[2], a, o2);
            o3 = fmaf((float)v[3], a, o3);
        }
        float4 res;
        res.x = fmaxf(o0 + bias1[c0 + 0], 0.f);
        res.y = fmaxf(o1 + bias1[c0 + 1], 0.f);
        res.z = fmaxf(o2 + bias1[c0 + 2], 0.f);
        res.w = fmaxf(o3 + bias1[c0 + 3], 0.f);
        *(float4*)&out[(size_t)(bg * NB + n) * 256 + c0] = res;
    }
}

extern "C" void kernel_launch(void* const* d_in, const int* in_sizes, int n_in,
                              void* d_out, int out_size, void* d_ws, size_t ws_size,
                              hipStream_t stream) {
    const float* x     = (const float*)d_in[0];
    const float* Wl0   = (const float*)d_in[1];
    const float* bl0   = (const float*)d_in[2];
    const float* Wr0   = (const float*)d_in[3];
    const float* br0   = (const float*)d_in[4];
    const float* att0  = (const float*)d_in[5];
    const float* bias0 = (const float*)d_in[6];
    const float* Wl1   = (const float*)d_in[7];
    const float* bl1   = (const float*)d_in[8];
    const float* Wr1   = (const float*)d_in[9];
    const float* br1   = (const float*)d_in[10];
    const float* att1  = (const float*)d_in[11];
    const float* bias1 = (const float*)d_in[12];
    __bf16* wt = (__bf16*)d_ws;   // 512 KB
    float* out = (float*)d_out;

    prep_weights<<<16, 256, 0, stream>>>(Wl0, Wr0, Wl1, Wr1, wt);
    gat_fused<<<NNODES / NB, 256, 0, stream>>>(x, bl0, br0, att0, bias0,
                                               bl1, br1, att1, bias1, wt, out);
}

// Round 3
// 369.462 us; speedup vs baseline: 1.3170x; 1.2605x over previous
//
#include <hip/hip_runtime.h>

// MetapathGATConv fused kernel for MI355X (gfx950) — R2.
// N=16384 nodes, R=8 relations, D=256, H=4, C=64 (HC=256).
// R2: NB=8 nodes/WG, 512 threads (8 waves), M=64 GEMMs (4x B-reuse per L2
// load), half the WGs -> half the L2 weight traffic, att0/att1 cached in
// LDS, broadcast-friendly P2 addressing (no per-lane rotation).

#define NNODES 16384
#define NB 8
#define MR 64              // rows per WG = NB*8

typedef __bf16 bf16x8 __attribute__((ext_vector_type(8)));
typedef __bf16 bf16x4 __attribute__((ext_vector_type(4)));
typedef float f32x4 __attribute__((ext_vector_type(4)));
typedef float f32x8 __attribute__((ext_vector_type(8)));

// swizzled chunk address: buffers are [rows][32 chunks of 8 bf16],
// chunk index XORed with (row&7) so column-strided accesses spread banks.
__device__ __forceinline__ int swz(int row, int chunk) {
    return row * 256 + ((chunk ^ (row & 7)) << 3);
}

// ---------------- weight prep: transpose+cast to bf16 W^T[n][k] ----------------
// wt rows 0-255: Wl0^T | 256-511: Wr0^T | 512-767: Wl1^T | 768-1023: Wr1^T.
// 64 blocks = 4 matrices x 4 k-tiles x 4 n-tiles; coalesced loads, LDS transpose.
__global__ void prep_weights(const float* __restrict__ Wl0, const float* __restrict__ Wr0,
                             const float* __restrict__ Wl1, const float* __restrict__ Wr1,
                             __bf16* __restrict__ wt) {
    __shared__ float tile[64 * 68];   // 64x64 + pad 4
    const int t  = threadIdx.x;
    const int m  = blockIdx.x >> 4;
    const int kt = (blockIdx.x >> 2) & 3;
    const int nt = blockIdx.x & 3;
    const float* src = (m == 0 ? Wl0 : m == 1 ? Wr0 : m == 2 ? Wl1 : Wr1) + kt * 64 * 256;
    #pragma unroll
    for (int i = 0; i < 4; ++i) {
        const int idx = i * 256 + t;     // float4 id 0..1023
        const int kk  = idx >> 4;
        const int nn  = (idx & 15) * 4;
        const float4 v = *(const float4*)&src[kk * 256 + nt * 64 + nn];
        tile[kk * 68 + nn + 0] = v.x;
        tile[kk * 68 + nn + 1] = v.y;
        tile[kk * 68 + nn + 2] = v.z;
        tile[kk * 68 + nn + 3] = v.w;
    }
    __syncthreads();
    const int n  = t >> 2;
    const int ks = (t & 3) * 16;
    bf16x8 o0, o1;
    #pragma unroll
    for (int e = 0; e < 8; ++e) o0[e] = (__bf16)tile[(ks + e) * 68 + n];
    #pragma unroll
    for (int e = 0; e < 8; ++e) o1[e] = (__bf16)tile[(ks + 8 + e) * 68 + n];
    __bf16* dst = &wt[(size_t)(m * 256 + nt * 64 + n) * 256 + kt * 64 + ks];
    *(bf16x8*)dst = o0;
    *(bf16x8*)(dst + 8) = o1;
}

__launch_bounds__(512, 4)
__global__ void gat_fused(const float* __restrict__ x,
                          const float* __restrict__ bl0, const float* __restrict__ br0,
                          const float* __restrict__ att0, const float* __restrict__ bias0,
                          const float* __restrict__ bl1, const float* __restrict__ br1,
                          const float* __restrict__ att1, const float* __restrict__ bias1,
                          const __bf16* __restrict__ wt,
                          float* __restrict__ out) {
    __shared__ __bf16 bufA[MR * 256];   // 32 KB: relu(x) -> xr0 -> h1
    __shared__ __bf16 bufB[MR * 256];   // 32 KB: xl0 -> xl1
    __shared__ float attbuf[2560];      // 10 KB: [0..2047] alpha0 -> xrs(f32)/alpha1
                                        //        [2048..2303] att0 cache -> logits1
                                        //        [2304..2559] att1 cache

    const int tid  = threadIdx.x;
    const int bg   = blockIdx.x;
    const int lane = tid & 63;
    const int wv   = tid >> 6;          // 0..7
    const int lr   = lane & 15;
    const int lq   = lane >> 4;

    // ---------------- P0: bufA = bf16(relu(x)); cache att0/att1 ----------------
    {
        const float4* src = (const float4*)(x + (size_t)bg * (MR * 256));
        #pragma unroll
        for (int it = 0; it < 4; ++it) {
            const int g   = it * 512 + tid;   // 8-elem chunk id, 0..2047
            const int row = g >> 5;
            const int c   = g & 31;
            const float4 v0 = src[2 * g];
            const float4 v1 = src[2 * g + 1];
            bf16x8 s;
            s[0] = (__bf16)fmaxf(v0.x, 0.f); s[1] = (__bf16)fmaxf(v0.y, 0.f);
            s[2] = (__bf16)fmaxf(v0.z, 0.f); s[3] = (__bf16)fmaxf(v0.w, 0.f);
            s[4] = (__bf16)fmaxf(v1.x, 0.f); s[5] = (__bf16)fmaxf(v1.y, 0.f);
            s[6] = (__bf16)fmaxf(v1.z, 0.f); s[7] = (__bf16)fmaxf(v1.w, 0.f);
            *(bf16x8*)&bufA[swz(row, c)] = s;
        }
        if (tid < 256) attbuf[2048 + tid] = att0[tid];
        else           attbuf[2048 + tid] = att1[tid - 256];
    }
    __syncthreads();

    // ---------------- P1: GEMM0 C[64][512] = relu(x) @ [Wl0|Wr0] ----------------
    // wave wv owns 64 N-cols (waves 0-3 -> xl/bufB, 4-7 -> xr/bufA), all 4 M-tiles.
    {
        f32x4 acc[4][4];
        #pragma unroll
        for (int m = 0; m < 4; ++m)
            #pragma unroll
            for (int n = 0; n < 4; ++n)
                acc[m][n] = f32x4{0.f, 0.f, 0.f, 0.f};
        #pragma unroll
        for (int kt = 0; kt < 8; ++kt) {
            bf16x8 a[4], b[4];
            #pragma unroll
            for (int m = 0; m < 4; ++m)
                a[m] = *(const bf16x8*)&bufA[swz(m * 16 + lr, kt * 4 + lq)];
            const int koff = kt * 32 + lq * 8;
            #pragma unroll
            for (int n = 0; n < 4; ++n)
                b[n] = *(const bf16x8*)&wt[(size_t)(wv * 64 + n * 16 + lr) * 256 + koff];
            #pragma unroll
            for (int m = 0; m < 4; ++m)
                #pragma unroll
                for (int n = 0; n < 4; ++n)
                    acc[m][n] = __builtin_amdgcn_mfma_f32_16x16x32_bf16(a[m], b[n], acc[m][n], 0, 0, 0);
        }
        __syncthreads();   // all A-reads of bufA done before xr overwrites it
        __bf16* dstbuf = (wv < 4) ? bufB : bufA;
        const float* bv = (wv < 4) ? bl0 : br0;
        #pragma unroll
        for (int n = 0; n < 4; ++n) {
            const int cl   = (wv & 3) * 64 + n * 16 + lr;   // 0..255 within dst buffer
            const float bias = bv[cl];
            const int ch   = cl >> 3, ce = cl & 7;
            #pragma unroll
            for (int m = 0; m < 4; ++m)
                #pragma unroll
                for (int r = 0; r < 4; ++r) {
                    const int row = m * 16 + lq * 4 + r;
                    dstbuf[swz(row, ch) + ce] = (__bf16)(acc[m][n][r] + bias);
                }
        }
    }
    __syncthreads();

    // ---------------- P2: layer-0 logits + softmax over j -> alpha0 ----------------
    // thread = (n=wave, i, h, jh): 4 j-logits each, pair-reduce via shfl_xor(1).
    {
        const int n  = tid >> 6;          // node 0..7
        const int i  = (tid >> 3) & 7;
        const int h  = (tid >> 1) & 3;
        const int jh = tid & 1;
        const int rowR = n * 8 + i;
        float lg[4] = {0.f, 0.f, 0.f, 0.f};
        #pragma unroll
        for (int cc = 0; cc < 8; ++cc) {
            const bf16x8 vr = *(const bf16x8*)&bufA[swz(rowR, h * 8 + cc)];
            const f32x8 xr = __builtin_convertvector(vr, f32x8);
            const float4 a0 = *(const float4*)&attbuf[2048 + h * 64 + cc * 8];
            const float4 a1 = *(const float4*)&attbuf[2048 + h * 64 + cc * 8 + 4];
            const float av[8] = {a0.x, a0.y, a0.z, a0.w, a1.x, a1.y, a1.z, a1.w};
            #pragma unroll
            for (int jj = 0; jj < 4; ++jj) {
                const int rowL = n * 8 + jh * 4 + jj;
                const bf16x8 vl = *(const bf16x8*)&bufB[swz(rowL, h * 8 + cc)];
                const f32x8 xl = __builtin_convertvector(vl, f32x8);
                #pragma unroll
                for (int e = 0; e < 8; ++e) {
                    float t = xr[e] + xl[e];
                    t = fmaxf(t, 0.2f * t);               // leaky_relu(0.2)
                    lg[jj] = fmaf(t, av[e], lg[jj]);
                }
            }
        }
        float mx = fmaxf(fmaxf(lg[0], lg[1]), fmaxf(lg[2], lg[3]));
        mx = fmaxf(mx, __shfl_xor(mx, 1));
        float ex[4], ssum = 0.f;
        #pragma unroll
        for (int jj = 0; jj < 4; ++jj) { ex[jj] = __expf(lg[jj] - mx); ssum += ex[jj]; }
        const float tot = ssum + __shfl_xor(ssum, 1);
        const float inv = 1.f / tot;
        #pragma unroll
        for (int jj = 0; jj < 4; ++jj)
            attbuf[((n * 8 + i) * 4 + h) * 8 + jh * 4 + jj] = ex[jj] * inv;
    }
    __syncthreads();

    // ---------------- P3: h1 = relu(alpha0 @ xl0 + bias0) -> bufA ----------------
    // thread = (row, h, half): 32 output cols.
    {
        const int row  = tid >> 3;        // 0..63
        const int sub  = tid & 7;
        const int h    = sub >> 1;
        const int half = sub & 1;
        const int cb   = h * 8 + half * 4;   // base chunk (of 4)
        const int nn   = row >> 3;
        float alpha[8];
        #pragma unroll
        for (int j = 0; j < 8; ++j) alpha[j] = attbuf[(row * 4 + h) * 8 + j];
        float o[32];
        #pragma unroll
        for (int c = 0; c < 32; ++c) o[c] = 0.f;
        #pragma unroll
        for (int j = 0; j < 8; ++j) {
            const int rowj = nn * 8 + j;
            #pragma unroll
            for (int cc = 0; cc < 4; ++cc) {
                const bf16x8 v = *(const bf16x8*)&bufB[swz(rowj, cb + cc)];
                const f32x8 f = __builtin_convertvector(v, f32x8);
                #pragma unroll
                for (int e = 0; e < 8; ++e)
                    o[cc * 8 + e] = fmaf(f[e], alpha[j], o[cc * 8 + e]);
            }
        }
        #pragma unroll
        for (int cc = 0; cc < 4; ++cc) {
            bf16x8 s;
            #pragma unroll
            for (int e = 0; e < 8; ++e) {
                const float v = o[cc * 8 + e] + bias0[(cb + cc) * 8 + e];
                s[e] = (__bf16)fmaxf(v, 0.f);
            }
            *(bf16x8*)&bufA[swz(row, cb + cc)] = s;
        }
    }
    __syncthreads();

    // ---------------- P5: GEMM1: xl1 = h1@Wl1+bl1 -> bufB ; xrs = self@Wr1+br1 -> attbuf ----------------
    // wave wv owns 32 cols of W1l (4 M-tiles) + 32 cols of W1r (self rows).
    {
        f32x4 accl[4][2], accr[2];
        #pragma unroll
        for (int m = 0; m < 4; ++m)
            #pragma unroll
            for (int n = 0; n < 2; ++n)
                accl[m][n] = f32x4{0.f, 0.f, 0.f, 0.f};
        #pragma unroll
        for (int n = 0; n < 2; ++n) accr[n] = f32x4{0.f, 0.f, 0.f, 0.f};
        const __bf16* W1l = wt + 512 * 256;
        const __bf16* W1r = wt + 768 * 256;
        const int rowS = (lr & 7) * 8 + 7;    // self row of node (lr&7)
        #pragma unroll
        for (int kt = 0; kt < 8; ++kt) {
            const int koff = kt * 32 + lq * 8;
            bf16x8 a[4], as, bl[2], br[2];
            #pragma unroll
            for (int m = 0; m < 4; ++m)
                a[m] = *(const bf16x8*)&bufA[swz(m * 16 + lr, kt * 4 + lq)];
            as = *(const bf16x8*)&bufA[swz(rowS, kt * 4 + lq)];
            #pragma unroll
            for (int n = 0; n < 2; ++n) {
                bl[n] = *(const bf16x8*)&W1l[(size_t)(wv * 32 + n * 16 + lr) * 256 + koff];
                br[n] = *(const bf16x8*)&W1r[(size_t)(wv * 32 + n * 16 + lr) * 256 + koff];
            }
            #pragma unroll
            for (int m = 0; m < 4; ++m)
                #pragma unroll
                for (int n = 0; n < 2; ++n)
                    accl[m][n] = __builtin_amdgcn_mfma_f32_16x16x32_bf16(a[m], bl[n], accl[m][n], 0, 0, 0);
            #pragma unroll
            for (int n = 0; n < 2; ++n)
                accr[n] = __builtin_amdgcn_mfma_f32_16x16x32_bf16(as, br[n], accr[n], 0, 0, 0);
        }
        // epilogue writes bufB (not read in P5) and attbuf[0..2047] (alpha0 dead)
        #pragma unroll
        for (int n = 0; n < 2; ++n) {
            const int col = wv * 32 + n * 16 + lr;   // 0..255
            const float b1 = bl1[col], b2 = br1[col];
            const int ch = col >> 3, ce = col & 7;
            #pragma unroll
            for (int m = 0; m < 4; ++m)
                #pragma unroll
                for (int r = 0; r < 4; ++r) {
                    const int row = m * 16 + lq * 4 + r;
                    bufB[swz(row, ch) + ce] = (__bf16)(accl[m][n][r] + b1);
                }
            if (lq < 2) {
                #pragma unroll
                for (int r = 0; r < 4; ++r) {        // D rows 0..7 = nodes 0..7
                    const int node = lq * 4 + r;
                    attbuf[node * 256 + col] = accr[n][r] + b2;   // xrs, f32
                }
            }
        }
    }
    __syncthreads();

    // ---------------- P6: layer-1 logits, softmax over r -> betas + alpha1 ----------------
    {
        const int n  = tid >> 5;
        const int rr = (tid >> 2) & 7;
        const int h  = tid & 3;
        float lg = 0.f;
        if (tid < 256) {
            const int rowj = n * 8 + rr;
            #pragma unroll
            for (int cc = 0; cc < 8; ++cc) {
                const float4 r0 = *(const float4*)&attbuf[n * 256 + h * 64 + cc * 8];
                const float4 r1 = *(const float4*)&attbuf[n * 256 + h * 64 + cc * 8 + 4];
                const float xr[8] = {r0.x, r0.y, r0.z, r0.w, r1.x, r1.y, r1.z, r1.w};
                const bf16x8 vl = *(const bf16x8*)&bufB[swz(rowj, h * 8 + cc)];
                const f32x8 xl = __builtin_convertvector(vl, f32x8);
                const float4 a0 = *(const float4*)&attbuf[2304 + h * 64 + cc * 8];
                const float4 a1 = *(const float4*)&attbuf[2304 + h * 64 + cc * 8 + 4];
                const float av[8] = {a0.x, a0.y, a0.z, a0.w, a1.x, a1.y, a1.z, a1.w};
                #pragma unroll
                for (int e = 0; e < 8; ++e) {
                    float t = xr[e] + xl[e];
                    t = fmaxf(t, 0.2f * t);
                    lg = fmaf(t, av[e], lg);
                }
            }
        }
        __syncthreads();   // xrs reads done; logits region [2048..2303] is dead att0 cache
        if (tid < 256) attbuf[2048 + tid] = lg;
        __syncthreads();
        if (tid < 256) {
            float M = -1e30f;
            float l[8];
            #pragma unroll
            for (int j = 0; j < 8; ++j) {
                l[j] = attbuf[2048 + n * 32 + j * 4 + h];
                M = fmaxf(M, l[j]);
            }
            float S = 0.f;
            #pragma unroll
            for (int j = 0; j < 8; ++j) S += __expf(l[j] - M);
            const float a = __expf(lg - M) / S;
            attbuf[tid] = a;    // alpha1 in [0..255] (xrs dead)
            out[(size_t)NNODES * 256 + (size_t)(bg * NB + n) * 32 + rr * 4 + h] = a;  // betas
        }
    }
    __syncthreads();

    // ---------------- P7: out = relu(alpha1 @ xl1 + bias1) ----------------
    {
        const int n  = tid >> 6;          // node 0..7
        const int q  = tid & 63;
        const int c0 = q * 4;
        const int h  = q >> 4;
        float o0 = 0.f, o1 = 0.f, o2 = 0.f, o3 = 0.f;
        #pragma unroll
        for (int r = 0; r < 8; ++r) {
            const float a = attbuf[n * 32 + r * 4 + h];
            const int rowj = n * 8 + r;
            const bf16x4 v = *(const bf16x4*)&bufB[swz(rowj, q >> 1) + (q & 1) * 4];
            o0 = fmaf((float)v[0], a, o0);
            o1 = fmaf((float)v[1], a, o1);
            o2 = fmaf((float)v[2], a, o2);
            o3 = fmaf((float)v[3], a, o3);
        }
        float4 res;
        res.x = fmaxf(o0 + bias1[c0 + 0], 0.f);
        res.y = fmaxf(o1 + bias1[c0 + 1], 0.f);
        res.z = fmaxf(o2 + bias1[c0 + 2], 0.f);
        res.w = fmaxf(o3 + bias1[c0 + 3], 0.f);
        *(float4*)&out[(size_t)(bg * NB + n) * 256 + c0] = res;
    }
}

extern "C" void kernel_launch(void* const* d_in, const int* in_sizes, int n_in,
                              void* d_out, int out_size, void* d_ws, size_t ws_size,
                              hipStream_t stream) {
    const float* x     = (const float*)d_in[0];
    const float* Wl0   = (const float*)d_in[1];
    const float* bl0   = (const float*)d_in[2];
    const float* Wr0   = (const float*)d_in[3];
    const float* br0   = (const float*)d_in[4];
    const float* att0  = (const float*)d_in[5];
    const float* bias0 = (const float*)d_in[6];
    const float* Wl1   = (const float*)d_in[7];
    const float* bl1   = (const float*)d_in[8];
    const float* Wr1   = (const float*)d_in[9];
    const float* br1   = (const float*)d_in[10];
    const float* att1  = (const float*)d_in[11];
    const float* bias1 = (const float*)d_in[12];
    __bf16* wt = (__bf16*)d_ws;   // 512 KB
    float* out = (float*)d_out;

    prep_weights<<<64, 256, 0, stream>>>(Wl0, Wr0, Wl1, Wr1, wt);
    gat_fused<<<NNODES / NB, 512, 0, stream>>>(x, bl0, br0, att0, bias0,
                                               bl1, br1, att1, bias1, wt, out);
}

// Round 5
// 353.086 us; speedup vs baseline: 1.3781x; 1.0464x over previous
//
#include <hip/hip_runtime.h>

// MetapathGATConv fused kernel for MI355X (gfx950) — R3b (compile fix).
// N=16384 nodes, R=8 relations, D=256, H=4, C=64 (HC=256).
// Full FP16 pipeline. Staged tensors (relu(x), xl, xr, h1, xl1) are f16
// in LDS; attention phases use packed f16 (v_pk_*) + v_dot2_f32_f16 with f32
// accumulation (no scalar cvt storm); GEMMs use mfma_f32_16x16x32_f16.
// Per-h chunk-phase rotation spreads LDS bank groups in P2/P3/P6.

#define NNODES 16384
#define NB 8
#define MR 64              // rows per WG = NB*8

typedef _Float16 f16x8 __attribute__((ext_vector_type(8)));
typedef _Float16 f16x4 __attribute__((ext_vector_type(4)));
typedef _Float16 f16x2 __attribute__((ext_vector_type(2)));
typedef float f32x4 __attribute__((ext_vector_type(4)));

#if __has_builtin(__builtin_amdgcn_fdot2)
#define FDOT2(a, b, c) __builtin_amdgcn_fdot2((a), (b), (c), false)
#else
#define FDOT2(a, b, c) ((c) + (float)(a)[0] * (float)(b)[0] + (float)(a)[1] * (float)(b)[1])
#endif

// cvt_pkrtz returns __fp16x2; bit_cast to our f16x2
__device__ __forceinline__ f16x2 pk2(float a, float b) {
    return __builtin_bit_cast(f16x2, __builtin_amdgcn_cvt_pkrtz(a, b));
}

__device__ __forceinline__ f16x2 leaky2(f16x2 t) {
#if __has_builtin(__builtin_elementwise_max)
    return __builtin_elementwise_max(t, t * (f16x2){(_Float16)0.2f, (_Float16)0.2f});
#else
    const unsigned u = __builtin_bit_cast(unsigned, t) & 0x7FFF7FFFu;
    const f16x2 at = __builtin_bit_cast(f16x2, u);
    return t * (f16x2){(_Float16)0.6f, (_Float16)0.6f} +
           at * (f16x2){(_Float16)0.4f, (_Float16)0.4f};
#endif
}
__device__ __forceinline__ f16x2 relu2(f16x2 t) {
#if __has_builtin(__builtin_elementwise_max)
    return __builtin_elementwise_max(t, (f16x2){(_Float16)0.f, (_Float16)0.f});
#else
    const unsigned u = __builtin_bit_cast(unsigned, t) & 0x7FFF7FFFu;
    const f16x2 at = __builtin_bit_cast(f16x2, u);
    return (t + at) * (f16x2){(_Float16)0.5f, (_Float16)0.5f};
#endif
}

// swizzled chunk address: buffers are [rows][32 chunks of 8 f16],
// chunk index XORed with (row&7) so column-strided accesses spread banks.
__device__ __forceinline__ int swz(int row, int chunk) {
    return row * 256 + ((chunk ^ (row & 7)) << 3);
}

// ---------------- weight prep: transpose+cast to f16 W^T[n][k] ----------------
// wt rows 0-255: Wl0^T | 256-511: Wr0^T | 512-767: Wl1^T | 768-1023: Wr1^T.
__global__ void prep_weights(const float* __restrict__ Wl0, const float* __restrict__ Wr0,
                             const float* __restrict__ Wl1, const float* __restrict__ Wr1,
                             _Float16* __restrict__ wt) {
    __shared__ float tile[64 * 68];   // 64x64 + pad 4
    const int t  = threadIdx.x;
    const int m  = blockIdx.x >> 4;
    const int kt = (blockIdx.x >> 2) & 3;
    const int nt = blockIdx.x & 3;
    const float* src = (m == 0 ? Wl0 : m == 1 ? Wr0 : m == 2 ? Wl1 : Wr1) + kt * 64 * 256;
    #pragma unroll
    for (int i = 0; i < 4; ++i) {
        const int idx = i * 256 + t;     // float4 id 0..1023
        const int kk  = idx >> 4;
        const int nn  = (idx & 15) * 4;
        const float4 v = *(const float4*)&src[kk * 256 + nt * 64 + nn];
        tile[kk * 68 + nn + 0] = v.x;
        tile[kk * 68 + nn + 1] = v.y;
        tile[kk * 68 + nn + 2] = v.z;
        tile[kk * 68 + nn + 3] = v.w;
    }
    __syncthreads();
    const int n  = t >> 2;
    const int ks = (t & 3) * 16;
    f16x8 o0, o1;
    #pragma unroll
    for (int e = 0; e < 8; ++e) o0[e] = (_Float16)tile[(ks + e) * 68 + n];
    #pragma unroll
    for (int e = 0; e < 8; ++e) o1[e] = (_Float16)tile[(ks + 8 + e) * 68 + n];
    _Float16* dst = &wt[(size_t)(m * 256 + nt * 64 + n) * 256 + kt * 64 + ks];
    *(f16x8*)dst = o0;
    *(f16x8*)(dst + 8) = o1;
}

__launch_bounds__(512, 4)
__global__ void gat_fused(const float* __restrict__ x,
                          const float* __restrict__ bl0, const float* __restrict__ br0,
                          const float* __restrict__ att0, const float* __restrict__ bias0,
                          const float* __restrict__ bl1, const float* __restrict__ br1,
                          const float* __restrict__ att1, const float* __restrict__ bias1,
                          const _Float16* __restrict__ wt,
                          float* __restrict__ out) {
    __shared__ _Float16 bufA[MR * 256];  // 32 KB: relu(x) -> xr0 -> h1
    __shared__ _Float16 bufB[MR * 256];  // 32 KB: xl0 -> xl1
    __shared__ float attbuf[2304];       // 9 KB: [0..2047] alpha0 -> xrs(f32) -> alpha1(0..255)
                                         //       [2048..2303] logits1
    __shared__ _Float16 attH[768];       // 1.5 KB: att0 | att1 | bias0 (f16)

    const int tid  = threadIdx.x;
    const int bg   = blockIdx.x;
    const int lane = tid & 63;
    const int wv   = tid >> 6;          // 0..7
    const int lr   = lane & 15;
    const int lq   = lane >> 4;

    // ---------------- P0: bufA = f16(relu(x)); cache att0/att1/bias0 as f16 ----------------
    {
        const float4* src = (const float4*)(x + (size_t)bg * (MR * 256));
        #pragma unroll
        for (int it = 0; it < 4; ++it) {
            const int g   = it * 512 + tid;   // 8-elem chunk id, 0..2047
            const int row = g >> 5;
            const int c   = g & 31;
            const float4 v0 = src[2 * g];
            const float4 v1 = src[2 * g + 1];
            f16x8 s;
            s[0] = (_Float16)fmaxf(v0.x, 0.f); s[1] = (_Float16)fmaxf(v0.y, 0.f);
            s[2] = (_Float16)fmaxf(v0.z, 0.f); s[3] = (_Float16)fmaxf(v0.w, 0.f);
            s[4] = (_Float16)fmaxf(v1.x, 0.f); s[5] = (_Float16)fmaxf(v1.y, 0.f);
            s[6] = (_Float16)fmaxf(v1.z, 0.f); s[7] = (_Float16)fmaxf(v1.w, 0.f);
            *(f16x8*)&bufA[swz(row, c)] = s;
        }
        if (tid < 256) {
            attH[tid]       = (_Float16)att0[tid];
            attH[512 + tid] = (_Float16)bias0[tid];
        } else {
            attH[tid]       = (_Float16)att1[tid - 256];   // att1 at [256..511]
        }
    }
    __syncthreads();

    // ---------------- P1: GEMM0 C[64][512] = relu(x) @ [Wl0|Wr0] ----------------
    // wave wv owns 64 N-cols (waves 0-3 -> xl/bufB, 4-7 -> xr/bufA), all 4 M-tiles.
    {
        f32x4 acc[4][4];
        #pragma unroll
        for (int m = 0; m < 4; ++m)
            #pragma unroll
            for (int n = 0; n < 4; ++n)
                acc[m][n] = f32x4{0.f, 0.f, 0.f, 0.f};
        #pragma unroll
        for (int kt = 0; kt < 8; ++kt) {
            f16x8 a[4], b[4];
            #pragma unroll
            for (int m = 0; m < 4; ++m)
                a[m] = *(const f16x8*)&bufA[swz(m * 16 + lr, kt * 4 + lq)];
            const int koff = kt * 32 + lq * 8;
            #pragma unroll
            for (int n = 0; n < 4; ++n)
                b[n] = *(const f16x8*)&wt[(size_t)(wv * 64 + n * 16 + lr) * 256 + koff];
            #pragma unroll
            for (int m = 0; m < 4; ++m)
                #pragma unroll
                for (int n = 0; n < 4; ++n)
                    acc[m][n] = __builtin_amdgcn_mfma_f32_16x16x32_f16(a[m], b[n], acc[m][n], 0, 0, 0);
        }
        __syncthreads();   // all A-reads of bufA done before xr overwrites it
        _Float16* dstbuf = (wv < 4) ? bufB : bufA;
        const float* bv = (wv < 4) ? bl0 : br0;
        #pragma unroll
        for (int n = 0; n < 4; ++n) {
            const int cl   = (wv & 3) * 64 + n * 16 + lr;   // 0..255 within dst buffer
            const float bias = bv[cl];
            const int ch   = cl >> 3, ce = cl & 7;
            #pragma unroll
            for (int m = 0; m < 4; ++m)
                #pragma unroll
                for (int r = 0; r < 4; ++r) {
                    const int row = m * 16 + lq * 4 + r;
                    dstbuf[swz(row, ch) + ce] = (_Float16)(acc[m][n][r] + bias);
                }
        }
    }
    __syncthreads();

    // ---------------- P2: layer-0 logits + softmax over j -> alpha0 ----------------
    // thread = (n, i, h, jh): 4 j-logits each via packed f16 + dot2, pair-reduce shfl_xor(1).
    {
        const int n  = tid >> 6;          // node 0..7
        const int i  = (tid >> 3) & 7;
        const int h  = (tid >> 1) & 3;
        const int jh = tid & 1;
        const int rowR = n * 8 + i;
        // preload xr row (8 chunks, per-h phase rotation)
        f16x2 xr2[32];
        #pragma unroll
        for (int cc = 0; cc < 8; ++cc) {
            const int c3 = (cc + 2 * h) & 7;
            const f16x8 v = *(const f16x8*)&bufA[swz(rowR, h * 8 + c3)];
            xr2[cc * 4 + 0] = f16x2{v[0], v[1]};
            xr2[cc * 4 + 1] = f16x2{v[2], v[3]};
            xr2[cc * 4 + 2] = f16x2{v[4], v[5]};
            xr2[cc * 4 + 3] = f16x2{v[6], v[7]};
        }
        float lg[4] = {0.f, 0.f, 0.f, 0.f};
        #pragma unroll
        for (int cc = 0; cc < 8; ++cc) {
            const int c3 = (cc + 2 * h) & 7;
            const f16x8 a8 = *(const f16x8*)&attH[h * 64 + c3 * 8];
            const f16x2 a2[4] = {{a8[0], a8[1]}, {a8[2], a8[3]}, {a8[4], a8[5]}, {a8[6], a8[7]}};
            #pragma unroll
            for (int jj = 0; jj < 4; ++jj) {
                const int rowL = n * 8 + jh * 4 + jj;
                const f16x8 l8 = *(const f16x8*)&bufB[swz(rowL, h * 8 + c3)];
                const f16x2 l2[4] = {{l8[0], l8[1]}, {l8[2], l8[3]}, {l8[4], l8[5]}, {l8[6], l8[7]}};
                #pragma unroll
                for (int p = 0; p < 4; ++p) {
                    const f16x2 t = leaky2(xr2[cc * 4 + p] + l2[p]);
                    lg[jj] = FDOT2(t, a2[p], lg[jj]);
                }
            }
        }
        float mx = fmaxf(fmaxf(lg[0], lg[1]), fmaxf(lg[2], lg[3]));
        mx = fmaxf(mx, __shfl_xor(mx, 1));
        float ex[4], ssum = 0.f;
        #pragma unroll
        for (int jj = 0; jj < 4; ++jj) { ex[jj] = __expf(lg[jj] - mx); ssum += ex[jj]; }
        const float tot = ssum + __shfl_xor(ssum, 1);
        const float inv = 1.f / tot;
        #pragma unroll
        for (int jj = 0; jj < 4; ++jj)
            attbuf[((n * 8 + i) * 4 + h) * 8 + jh * 4 + jj] = ex[jj] * inv;
    }
    __syncthreads();

    // ---------------- P3: h1 = relu(alpha0 @ xl0 + bias0) -> bufA (packed f16) ----------------
    // thread = (row, h, half): 32 output cols; per-h chunk phase.
    {
        const int row  = tid >> 3;        // 0..63
        const int sub  = tid & 7;
        const int h    = sub >> 1;
        const int half = sub & 1;
        const int nn   = row >> 3;
        f16x2 acc2[16];
        #pragma unroll
        for (int p = 0; p < 16; ++p) acc2[p] = (f16x2){(_Float16)0.f, (_Float16)0.f};
        #pragma unroll
        for (int j = 0; j < 8; ++j) {
            const _Float16 ah = (_Float16)attbuf[(row * 4 + h) * 8 + j];
            const f16x2 a2 = {ah, ah};
            const int rowj = nn * 8 + j;
            #pragma unroll
            for (int cc = 0; cc < 4; ++cc) {
                const int c = h * 8 + half * 4 + ((cc + h) & 3);
                const f16x8 v = *(const f16x8*)&bufB[swz(rowj, c)];
                acc2[cc * 4 + 0] += f16x2{v[0], v[1]} * a2;
                acc2[cc * 4 + 1] += f16x2{v[2], v[3]} * a2;
                acc2[cc * 4 + 2] += f16x2{v[4], v[5]} * a2;
                acc2[cc * 4 + 3] += f16x2{v[6], v[7]} * a2;
            }
        }
        #pragma unroll
        for (int cc = 0; cc < 4; ++cc) {
            const int c = h * 8 + half * 4 + ((cc + h) & 3);
            const f16x8 b8 = *(const f16x8*)&attH[512 + c * 8];
            f16x8 s;
            #pragma unroll
            for (int p = 0; p < 4; ++p) {
                const f16x2 r = relu2(acc2[cc * 4 + p] + f16x2{b8[2 * p], b8[2 * p + 1]});
                s[2 * p]     = r[0];
                s[2 * p + 1] = r[1];
            }
            *(f16x8*)&bufA[swz(row, c)] = s;
        }
    }
    __syncthreads();

    // ---------------- P5: GEMM1: xl1 = h1@Wl1+bl1 -> bufB ; xrs = self@Wr1+br1 -> attbuf ----------------
    {
        f32x4 accl[4][2], accr[2];
        #pragma unroll
        for (int m = 0; m < 4; ++m)
            #pragma unroll
            for (int n = 0; n < 2; ++n)
                accl[m][n] = f32x4{0.f, 0.f, 0.f, 0.f};
        #pragma unroll
        for (int n = 0; n < 2; ++n) accr[n] = f32x4{0.f, 0.f, 0.f, 0.f};
        const _Float16* W1l = wt + 512 * 256;
        const _Float16* W1r = wt + 768 * 256;
        const int rowS = (lr & 7) * 8 + 7;    // self row of node (lr&7)
        #pragma unroll
        for (int kt = 0; kt < 8; ++kt) {
            const int koff = kt * 32 + lq * 8;
            f16x8 a[4], as, bl[2], br[2];
            #pragma unroll
            for (int m = 0; m < 4; ++m)
                a[m] = *(const f16x8*)&bufA[swz(m * 16 + lr, kt * 4 + lq)];
            as = *(const f16x8*)&bufA[swz(rowS, kt * 4 + lq)];
            #pragma unroll
            for (int n = 0; n < 2; ++n) {
                bl[n] = *(const f16x8*)&W1l[(size_t)(wv * 32 + n * 16 + lr) * 256 + koff];
                br[n] = *(const f16x8*)&W1r[(size_t)(wv * 32 + n * 16 + lr) * 256 + koff];
            }
            #pragma unroll
            for (int m = 0; m < 4; ++m)
                #pragma unroll
                for (int n = 0; n < 2; ++n)
                    accl[m][n] = __builtin_amdgcn_mfma_f32_16x16x32_f16(a[m], bl[n], accl[m][n], 0, 0, 0);
            #pragma unroll
            for (int n = 0; n < 2; ++n)
                accr[n] = __builtin_amdgcn_mfma_f32_16x16x32_f16(as, br[n], accr[n], 0, 0, 0);
        }
        // epilogue writes bufB (not read in P5) and attbuf[0..2047] (alpha0 dead)
        #pragma unroll
        for (int n = 0; n < 2; ++n) {
            const int col = wv * 32 + n * 16 + lr;   // 0..255
            const float b1 = bl1[col], b2 = br1[col];
            const int ch = col >> 3, ce = col & 7;
            #pragma unroll
            for (int m = 0; m < 4; ++m)
                #pragma unroll
                for (int r = 0; r < 4; ++r) {
                    const int row = m * 16 + lq * 4 + r;
                    bufB[swz(row, ch) + ce] = (_Float16)(accl[m][n][r] + b1);
                }
            if (lq < 2) {
                #pragma unroll
                for (int r = 0; r < 4; ++r) {        // D rows 0..7 = nodes 0..7
                    const int node = lq * 4 + r;
                    attbuf[node * 256 + col] = accr[n][r] + b2;   // xrs, f32
                }
            }
        }
    }
    __syncthreads();

    // ---------------- P6: layer-1 logits, softmax over r -> betas + alpha1 ----------------
    {
        const int n  = tid >> 5;
        const int rr = (tid >> 2) & 7;
        const int h  = tid & 3;
        float lg = 0.f;
        if (tid < 256) {
            const int rowj = n * 8 + rr;
            #pragma unroll
            for (int cc = 0; cc < 8; ++cc) {
                const int c3 = (cc + 2 * h) & 7;
                const int c  = h * 8 + c3;
                const float4 r0 = *(const float4*)&attbuf[n * 256 + c * 8];
                const float4 r1 = *(const float4*)&attbuf[n * 256 + c * 8 + 4];
                const f16x2 x2[4] = {pk2(r0.x, r0.y), pk2(r0.z, r0.w),
                                     pk2(r1.x, r1.y), pk2(r1.z, r1.w)};
                const f16x8 l8 = *(const f16x8*)&bufB[swz(rowj, c)];
                const f16x2 l2[4] = {{l8[0], l8[1]}, {l8[2], l8[3]}, {l8[4], l8[5]}, {l8[6], l8[7]}};
                const f16x8 a8 = *(const f16x8*)&attH[256 + c * 8];
                const f16x2 a2[4] = {{a8[0], a8[1]}, {a8[2], a8[3]}, {a8[4], a8[5]}, {a8[6], a8[7]}};
                #pragma unroll
                for (int p = 0; p < 4; ++p) {
                    const f16x2 t = leaky2(x2[p] + l2[p]);
                    lg = FDOT2(t, a2[p], lg);
                }
            }
        }
        __syncthreads();   // xrs reads done
        if (tid < 256) attbuf[2048 + tid] = lg;
        __syncthreads();
        if (tid < 256) {
            float M = -1e30f;
            float l[8];
            #pragma unroll
            for (int j = 0; j < 8; ++j) {
                l[j] = attbuf[2048 + n * 32 + j * 4 + h];
                M = fmaxf(M, l[j]);
            }
            float S = 0.f;
            #pragma unroll
            for (int j = 0; j < 8; ++j) S += __expf(l[j] - M);
            const float a = __expf(lg - M) / S;
            attbuf[tid] = a;    // alpha1 in [0..255] (xrs dead)
            out[(size_t)NNODES * 256 + (size_t)(bg * NB + n) * 32 + rr * 4 + h] = a;  // betas
        }
    }
    __syncthreads();

    // ---------------- P7: out = relu(alpha1 @ xl1 + bias1) ----------------
    {
        const int n  = tid >> 6;          // node 0..7
        const int q  = tid & 63;
        const int c0 = q * 4;
        const int h  = q >> 4;
        float o0 = 0.f, o1 = 0.f, o2 = 0.f, o3 = 0.f;
        #pragma unroll
        for (int r = 0; r < 8; ++r) {
            const float a = attbuf[n * 32 + r * 4 + h];
            const int rowj = n * 8 + r;
            const f16x4 v = *(const f16x4*)&bufB[swz(rowj, q >> 1) + (q & 1) * 4];
            o0 = fmaf((float)v[0], a, o0);
            o1 = fmaf((float)v[1], a, o1);
            o2 = fmaf((float)v[2], a, o2);
            o3 = fmaf((float)v[3], a, o3);
        }
        float4 res;
        res.x = fmaxf(o0 + bias1[c0 + 0], 0.f);
        res.y = fmaxf(o1 + bias1[c0 + 1], 0.f);
        res.z = fmaxf(o2 + bias1[c0 + 2], 0.f);
        res.w = fmaxf(o3 + bias1[c0 + 3], 0.f);
        *(float4*)&out[(size_t)(bg * NB + n) * 256 + c0] = res;
    }
}

extern "C" void kernel_launch(void* const* d_in, const int* in_sizes, int n_in,
                              void* d_out, int out_size, void* d_ws, size_t ws_size,
                              hipStream_t stream) {
    const float* x     = (const float*)d_in[0];
    const float* Wl0   = (const float*)d_in[1];
    const float* bl0   = (const float*)d_in[2];
    const float* Wr0   = (const float*)d_in[3];
    const float* br0   = (const float*)d_in[4];
    const float* att0  = (const float*)d_in[5];
    const float* bias0 = (const float*)d_in[6];
    const float* Wl1   = (const float*)d_in[7];
    const float* bl1   = (const float*)d_in[8];
    const float* Wr1   = (const float*)d_in[9];
    const float* br1   = (const float*)d_in[10];
    const float* att1  = (const float*)d_in[11];
    const float* bias1 = (const float*)d_in[12];
    _Float16* wt = (_Float16*)d_ws;   // 512 KB
    float* out = (float*)d_out;

    prep_weights<<<64, 256, 0, stream>>>(Wl0, Wr0, Wl1, Wr1, wt);
    gat_fused<<<NNODES / NB, 512, 0, stream>>>(x, bl0, br0, att0, bias0,
                                               bl1, br1, att1, bias1, wt, out);
}

// Round 6
// 349.465 us; speedup vs baseline: 1.3924x; 1.0104x over previous
//
#include <hip/hip_runtime.h>

// MetapathGATConv fused kernel for MI355X (gfx950) — R4.
// Full FP16 pipeline (R3b) + explicit double-buffered LDS prefetch in the
// attention phases (P2/P3/P6/P7). Rationale: at 2 WG/CU the per-wave
// ds_read->use chains expose ~120cyc LDS latency (VGPR_Count=64 showed the
// compiler wasn't prefetching); batching 4-5 reads + 1-iteration-deep
// pipelining raises per-wave duty cycle. LDS binds occupancy (2 WG/CU), so
// VGPRs up to 128 are free under __launch_bounds__(512,4).

#define NNODES 16384
#define NB 8
#define MR 64              // rows per WG = NB*8

typedef _Float16 f16x8 __attribute__((ext_vector_type(8)));
typedef _Float16 f16x4 __attribute__((ext_vector_type(4)));
typedef _Float16 f16x2 __attribute__((ext_vector_type(2)));
typedef float f32x4 __attribute__((ext_vector_type(4)));

#if __has_builtin(__builtin_amdgcn_fdot2)
#define FDOT2(a, b, c) __builtin_amdgcn_fdot2((a), (b), (c), false)
#else
#define FDOT2(a, b, c) ((c) + (float)(a)[0] * (float)(b)[0] + (float)(a)[1] * (float)(b)[1])
#endif

// cvt_pkrtz returns __fp16x2; bit_cast to our f16x2
__device__ __forceinline__ f16x2 pk2(float a, float b) {
    return __builtin_bit_cast(f16x2, __builtin_amdgcn_cvt_pkrtz(a, b));
}

__device__ __forceinline__ f16x2 leaky2(f16x2 t) {
#if __has_builtin(__builtin_elementwise_max)
    return __builtin_elementwise_max(t, t * (f16x2){(_Float16)0.2f, (_Float16)0.2f});
#else
    const unsigned u = __builtin_bit_cast(unsigned, t) & 0x7FFF7FFFu;
    const f16x2 at = __builtin_bit_cast(f16x2, u);
    return t * (f16x2){(_Float16)0.6f, (_Float16)0.6f} +
           at * (f16x2){(_Float16)0.4f, (_Float16)0.4f};
#endif
}
__device__ __forceinline__ f16x2 relu2(f16x2 t) {
#if __has_builtin(__builtin_elementwise_max)
    return __builtin_elementwise_max(t, (f16x2){(_Float16)0.f, (_Float16)0.f});
#else
    const unsigned u = __builtin_bit_cast(unsigned, t) & 0x7FFF7FFFu;
    const f16x2 at = __builtin_bit_cast(f16x2, u);
    return (t + at) * (f16x2){(_Float16)0.5f, (_Float16)0.5f};
#endif
}

// swizzled chunk address: buffers are [rows][32 chunks of 8 f16],
// chunk index XORed with (row&7) so column-strided accesses spread banks.
__device__ __forceinline__ int swz(int row, int chunk) {
    return row * 256 + ((chunk ^ (row & 7)) << 3);
}

// ---------------- weight prep: transpose+cast to f16 W^T[n][k] ----------------
// wt rows 0-255: Wl0^T | 256-511: Wr0^T | 512-767: Wl1^T | 768-1023: Wr1^T.
__global__ void prep_weights(const float* __restrict__ Wl0, const float* __restrict__ Wr0,
                             const float* __restrict__ Wl1, const float* __restrict__ Wr1,
                             _Float16* __restrict__ wt) {
    __shared__ float tile[64 * 68];   // 64x64 + pad 4
    const int t  = threadIdx.x;
    const int m  = blockIdx.x >> 4;
    const int kt = (blockIdx.x >> 2) & 3;
    const int nt = blockIdx.x & 3;
    const float* src = (m == 0 ? Wl0 : m == 1 ? Wr0 : m == 2 ? Wl1 : Wr1) + kt * 64 * 256;
    #pragma unroll
    for (int i = 0; i < 4; ++i) {
        const int idx = i * 256 + t;     // float4 id 0..1023
        const int kk  = idx >> 4;
        const int nn  = (idx & 15) * 4;
        const float4 v = *(const float4*)&src[kk * 256 + nt * 64 + nn];
        tile[kk * 68 + nn + 0] = v.x;
        tile[kk * 68 + nn + 1] = v.y;
        tile[kk * 68 + nn + 2] = v.z;
        tile[kk * 68 + nn + 3] = v.w;
    }
    __syncthreads();
    const int n  = t >> 2;
    const int ks = (t & 3) * 16;
    f16x8 o0, o1;
    #pragma unroll
    for (int e = 0; e < 8; ++e) o0[e] = (_Float16)tile[(ks + e) * 68 + n];
    #pragma unroll
    for (int e = 0; e < 8; ++e) o1[e] = (_Float16)tile[(ks + 8 + e) * 68 + n];
    _Float16* dst = &wt[(size_t)(m * 256 + nt * 64 + n) * 256 + kt * 64 + ks];
    *(f16x8*)dst = o0;
    *(f16x8*)(dst + 8) = o1;
}

__launch_bounds__(512, 4)
__global__ void gat_fused(const float* __restrict__ x,
                          const float* __restrict__ bl0, const float* __restrict__ br0,
                          const float* __restrict__ att0, const float* __restrict__ bias0,
                          const float* __restrict__ bl1, const float* __restrict__ br1,
                          const float* __restrict__ att1, const float* __restrict__ bias1,
                          const _Float16* __restrict__ wt,
                          float* __restrict__ out) {
    __shared__ _Float16 bufA[MR * 256];  // 32 KB: relu(x) -> xr0 -> h1
    __shared__ _Float16 bufB[MR * 256];  // 32 KB: xl0 -> xl1
    __shared__ float attbuf[2304];       // 9 KB: [0..2047] alpha0 -> xrs(f32) -> alpha1(0..255)
                                         //       [2048..2303] logits1
    __shared__ _Float16 attH[768];       // 1.5 KB: att0 | att1 | bias0 (f16)

    const int tid  = threadIdx.x;
    const int bg   = blockIdx.x;
    const int lane = tid & 63;
    const int wv   = tid >> 6;          // 0..7
    const int lr   = lane & 15;
    const int lq   = lane >> 4;

    // ---------------- P0: bufA = f16(relu(x)); cache att0/att1/bias0 as f16 ----------------
    {
        const float4* src = (const float4*)(x + (size_t)bg * (MR * 256));
        #pragma unroll
        for (int it = 0; it < 4; ++it) {
            const int g   = it * 512 + tid;   // 8-elem chunk id, 0..2047
            const int row = g >> 5;
            const int c   = g & 31;
            const float4 v0 = src[2 * g];
            const float4 v1 = src[2 * g + 1];
            f16x8 s;
            s[0] = (_Float16)fmaxf(v0.x, 0.f); s[1] = (_Float16)fmaxf(v0.y, 0.f);
            s[2] = (_Float16)fmaxf(v0.z, 0.f); s[3] = (_Float16)fmaxf(v0.w, 0.f);
            s[4] = (_Float16)fmaxf(v1.x, 0.f); s[5] = (_Float16)fmaxf(v1.y, 0.f);
            s[6] = (_Float16)fmaxf(v1.z, 0.f); s[7] = (_Float16)fmaxf(v1.w, 0.f);
            *(f16x8*)&bufA[swz(row, c)] = s;
        }
        if (tid < 256) {
            attH[tid]       = (_Float16)att0[tid];
            attH[512 + tid] = (_Float16)bias0[tid];
        } else {
            attH[tid]       = (_Float16)att1[tid - 256];   // att1 at [256..511]
        }
    }
    __syncthreads();

    // ---------------- P1: GEMM0 C[64][512] = relu(x) @ [Wl0|Wr0] ----------------
    // wave wv owns 64 N-cols (waves 0-3 -> xl/bufB, 4-7 -> xr/bufA), all 4 M-tiles.
    {
        f32x4 acc[4][4];
        #pragma unroll
        for (int m = 0; m < 4; ++m)
            #pragma unroll
            for (int n = 0; n < 4; ++n)
                acc[m][n] = f32x4{0.f, 0.f, 0.f, 0.f};
        #pragma unroll
        for (int kt = 0; kt < 8; ++kt) {
            f16x8 a[4], b[4];
            #pragma unroll
            for (int m = 0; m < 4; ++m)
                a[m] = *(const f16x8*)&bufA[swz(m * 16 + lr, kt * 4 + lq)];
            const int koff = kt * 32 + lq * 8;
            #pragma unroll
            for (int n = 0; n < 4; ++n)
                b[n] = *(const f16x8*)&wt[(size_t)(wv * 64 + n * 16 + lr) * 256 + koff];
            #pragma unroll
            for (int m = 0; m < 4; ++m)
                #pragma unroll
                for (int n = 0; n < 4; ++n)
                    acc[m][n] = __builtin_amdgcn_mfma_f32_16x16x32_f16(a[m], b[n], acc[m][n], 0, 0, 0);
        }
        __syncthreads();   // all A-reads of bufA done before xr overwrites it
        _Float16* dstbuf = (wv < 4) ? bufB : bufA;
        const float* bv = (wv < 4) ? bl0 : br0;
        #pragma unroll
        for (int n = 0; n < 4; ++n) {
            const int cl   = (wv & 3) * 64 + n * 16 + lr;   // 0..255 within dst buffer
            const float bias = bv[cl];
            const int ch   = cl >> 3, ce = cl & 7;
            #pragma unroll
            for (int m = 0; m < 4; ++m)
                #pragma unroll
                for (int r = 0; r < 4; ++r) {
                    const int row = m * 16 + lq * 4 + r;
                    dstbuf[swz(row, ch) + ce] = (_Float16)(acc[m][n][r] + bias);
                }
        }
    }
    __syncthreads();

    // ---------------- P2: layer-0 logits + softmax over j -> alpha0 ----------------
    // thread = (n, i, h, jh): 4 j-logits. Double-buffered prefetch over cc:
    // issue the 5 reads (4 xl + 1 att) for cc+1 before computing cc.
    {
        const int n  = tid >> 6;          // node 0..7
        const int i  = (tid >> 3) & 7;
        const int h  = (tid >> 1) & 3;
        const int jh = tid & 1;
        const int rowR = n * 8 + i;
        // preload xr row (8 chunks, per-h phase rotation) — independent reads
        f16x2 xr2[32];
        #pragma unroll
        for (int cc = 0; cc < 8; ++cc) {
            const int c3 = (cc + 2 * h) & 7;
            const f16x8 v = *(const f16x8*)&bufA[swz(rowR, h * 8 + c3)];
            xr2[cc * 4 + 0] = f16x2{v[0], v[1]};
            xr2[cc * 4 + 1] = f16x2{v[2], v[3]};
            xr2[cc * 4 + 2] = f16x2{v[4], v[5]};
            xr2[cc * 4 + 3] = f16x2{v[6], v[7]};
        }
        f16x8 lbuf[2][4];
        f16x8 abuf[2];
        {
            const int c3 = (2 * h) & 7;
            abuf[0] = *(const f16x8*)&attH[h * 64 + c3 * 8];
            #pragma unroll
            for (int jj = 0; jj < 4; ++jj)
                lbuf[0][jj] = *(const f16x8*)&bufB[swz(n * 8 + jh * 4 + jj, h * 8 + c3)];
        }
        float lg[4] = {0.f, 0.f, 0.f, 0.f};
        #pragma unroll
        for (int cc = 0; cc < 8; ++cc) {
            const int cur = cc & 1, nxt = cur ^ 1;
            if (cc < 7) {
                const int c3n = (cc + 1 + 2 * h) & 7;
                abuf[nxt] = *(const f16x8*)&attH[h * 64 + c3n * 8];
                #pragma unroll
                for (int jj = 0; jj < 4; ++jj)
                    lbuf[nxt][jj] = *(const f16x8*)&bufB[swz(n * 8 + jh * 4 + jj, h * 8 + c3n)];
            }
            const f16x8 a8 = abuf[cur];
            const f16x2 a2[4] = {{a8[0], a8[1]}, {a8[2], a8[3]}, {a8[4], a8[5]}, {a8[6], a8[7]}};
            #pragma unroll
            for (int jj = 0; jj < 4; ++jj) {
                const f16x8 l8 = lbuf[cur][jj];
                const f16x2 l2[4] = {{l8[0], l8[1]}, {l8[2], l8[3]}, {l8[4], l8[5]}, {l8[6], l8[7]}};
                #pragma unroll
                for (int p = 0; p < 4; ++p) {
                    const f16x2 t = leaky2(xr2[cc * 4 + p] + l2[p]);
                    lg[jj] = FDOT2(t, a2[p], lg[jj]);
                }
            }
        }
        float mx = fmaxf(fmaxf(lg[0], lg[1]), fmaxf(lg[2], lg[3]));
        mx = fmaxf(mx, __shfl_xor(mx, 1));
        float ex[4], ssum = 0.f;
        #pragma unroll
        for (int jj = 0; jj < 4; ++jj) { ex[jj] = __expf(lg[jj] - mx); ssum += ex[jj]; }
        const float tot = ssum + __shfl_xor(ssum, 1);
        const float inv = 1.f / tot;
        #pragma unroll
        for (int jj = 0; jj < 4; ++jj)
            attbuf[((n * 8 + i) * 4 + h) * 8 + jh * 4 + jj] = ex[jj] * inv;
    }
    __syncthreads();

    // ---------------- P3: h1 = relu(alpha0 @ xl0 + bias0) -> bufA (packed f16) ----------------
    // thread = (row, h, half): 32 output cols; j-loop double-buffered (prefetch j+1's 4 reads).
    {
        const int row  = tid >> 3;        // 0..63
        const int sub  = tid & 7;
        const int h    = sub >> 1;
        const int half = sub & 1;
        const int nn   = row >> 3;
        const int cb   = h * 8 + half * 4;
        _Float16 ahv[8];
        #pragma unroll
        for (int j = 0; j < 8; ++j) ahv[j] = (_Float16)attbuf[(row * 4 + h) * 8 + j];
        f16x2 acc2[16];
        #pragma unroll
        for (int p = 0; p < 16; ++p) acc2[p] = (f16x2){(_Float16)0.f, (_Float16)0.f};
        f16x8 vbuf[2][4];
        #pragma unroll
        for (int cc = 0; cc < 4; ++cc)
            vbuf[0][cc] = *(const f16x8*)&bufB[swz(nn * 8, cb + ((cc + h) & 3))];
        #pragma unroll
        for (int j = 0; j < 8; ++j) {
            const int cur = j & 1, nxt = cur ^ 1;
            if (j < 7) {
                #pragma unroll
                for (int cc = 0; cc < 4; ++cc)
                    vbuf[nxt][cc] = *(const f16x8*)&bufB[swz(nn * 8 + j + 1, cb + ((cc + h) & 3))];
            }
            const f16x2 a2 = {ahv[j], ahv[j]};
            #pragma unroll
            for (int cc = 0; cc < 4; ++cc) {
                const f16x8 v = vbuf[cur][cc];
                acc2[cc * 4 + 0] += f16x2{v[0], v[1]} * a2;
                acc2[cc * 4 + 1] += f16x2{v[2], v[3]} * a2;
                acc2[cc * 4 + 2] += f16x2{v[4], v[5]} * a2;
                acc2[cc * 4 + 3] += f16x2{v[6], v[7]} * a2;
            }
        }
        #pragma unroll
        for (int cc = 0; cc < 4; ++cc) {
            const int c = cb + ((cc + h) & 3);
            const f16x8 b8 = *(const f16x8*)&attH[512 + c * 8];
            f16x8 s;
            #pragma unroll
            for (int p = 0; p < 4; ++p) {
                const f16x2 r = relu2(acc2[cc * 4 + p] + f16x2{b8[2 * p], b8[2 * p + 1]});
                s[2 * p]     = r[0];
                s[2 * p + 1] = r[1];
            }
            *(f16x8*)&bufA[swz(row, c)] = s;
        }
    }
    __syncthreads();

    // ---------------- P5: GEMM1: xl1 = h1@Wl1+bl1 -> bufB ; xrs = self@Wr1+br1 -> attbuf ----------------
    {
        f32x4 accl[4][2], accr[2];
        #pragma unroll
        for (int m = 0; m < 4; ++m)
            #pragma unroll
            for (int n = 0; n < 2; ++n)
                accl[m][n] = f32x4{0.f, 0.f, 0.f, 0.f};
        #pragma unroll
        for (int n = 0; n < 2; ++n) accr[n] = f32x4{0.f, 0.f, 0.f, 0.f};
        const _Float16* W1l = wt + 512 * 256;
        const _Float16* W1r = wt + 768 * 256;
        const int rowS = (lr & 7) * 8 + 7;    // self row of node (lr&7)
        #pragma unroll
        for (int kt = 0; kt < 8; ++kt) {
            const int koff = kt * 32 + lq * 8;
            f16x8 a[4], as, bl[2], br[2];
            #pragma unroll
            for (int m = 0; m < 4; ++m)
                a[m] = *(const f16x8*)&bufA[swz(m * 16 + lr, kt * 4 + lq)];
            as = *(const f16x8*)&bufA[swz(rowS, kt * 4 + lq)];
            #pragma unroll
            for (int n = 0; n < 2; ++n) {
                bl[n] = *(const f16x8*)&W1l[(size_t)(wv * 32 + n * 16 + lr) * 256 + koff];
                br[n] = *(const f16x8*)&W1r[(size_t)(wv * 32 + n * 16 + lr) * 256 + koff];
            }
            #pragma unroll
            for (int m = 0; m < 4; ++m)
                #pragma unroll
                for (int n = 0; n < 2; ++n)
                    accl[m][n] = __builtin_amdgcn_mfma_f32_16x16x32_f16(a[m], bl[n], accl[m][n], 0, 0, 0);
            #pragma unroll
            for (int n = 0; n < 2; ++n)
                accr[n] = __builtin_amdgcn_mfma_f32_16x16x32_f16(as, br[n], accr[n], 0, 0, 0);
        }
        // epilogue writes bufB (not read in P5) and attbuf[0..2047] (alpha0 dead)
        #pragma unroll
        for (int n = 0; n < 2; ++n) {
            const int col = wv * 32 + n * 16 + lr;   // 0..255
            const float b1 = bl1[col], b2 = br1[col];
            const int ch = col >> 3, ce = col & 7;
            #pragma unroll
            for (int m = 0; m < 4; ++m)
                #pragma unroll
                for (int r = 0; r < 4; ++r) {
                    const int row = m * 16 + lq * 4 + r;
                    bufB[swz(row, ch) + ce] = (_Float16)(accl[m][n][r] + b1);
                }
            if (lq < 2) {
                #pragma unroll
                for (int r = 0; r < 4; ++r) {        // D rows 0..7 = nodes 0..7
                    const int node = lq * 4 + r;
                    attbuf[node * 256 + col] = accr[n][r] + b2;   // xrs, f32
                }
            }
        }
    }
    __syncthreads();

    // ---------------- P6: layer-1 logits, softmax over r -> betas + alpha1 ----------------
    // Double-buffered prefetch over cc (2 xrs float4 + 1 xl1 + 1 att per step).
    {
        const int n  = tid >> 5;
        const int rr = (tid >> 2) & 7;
        const int h  = tid & 3;
        float lg = 0.f;
        if (tid < 256) {
            const int rowj = n * 8 + rr;
            float4 xbuf0[2], xbuf1[2];
            f16x8 lbuf[2], abuf[2];
            {
                const int c = h * 8 + ((2 * h) & 7);
                xbuf0[0] = *(const float4*)&attbuf[n * 256 + c * 8];
                xbuf1[0] = *(const float4*)&attbuf[n * 256 + c * 8 + 4];
                lbuf[0]  = *(const f16x8*)&bufB[swz(rowj, c)];
                abuf[0]  = *(const f16x8*)&attH[256 + c * 8];
            }
            #pragma unroll
            for (int cc = 0; cc < 8; ++cc) {
                const int cur = cc & 1, nxt = cur ^ 1;
                if (cc < 7) {
                    const int cn = h * 8 + ((cc + 1 + 2 * h) & 7);
                    xbuf0[nxt] = *(const float4*)&attbuf[n * 256 + cn * 8];
                    xbuf1[nxt] = *(const float4*)&attbuf[n * 256 + cn * 8 + 4];
                    lbuf[nxt]  = *(const f16x8*)&bufB[swz(rowj, cn)];
                    abuf[nxt]  = *(const f16x8*)&attH[256 + cn * 8];
                }
                const float4 r0 = xbuf0[cur], r1 = xbuf1[cur];
                const f16x2 x2[4] = {pk2(r0.x, r0.y), pk2(r0.z, r0.w),
                                     pk2(r1.x, r1.y), pk2(r1.z, r1.w)};
                const f16x8 l8 = lbuf[cur];
                const f16x2 l2[4] = {{l8[0], l8[1]}, {l8[2], l8[3]}, {l8[4], l8[5]}, {l8[6], l8[7]}};
                const f16x8 a8 = abuf[cur];
                const f16x2 a2[4] = {{a8[0], a8[1]}, {a8[2], a8[3]}, {a8[4], a8[5]}, {a8[6], a8[7]}};
                #pragma unroll
                for (int p = 0; p < 4; ++p) {
                    const f16x2 t = leaky2(x2[p] + l2[p]);
                    lg = FDOT2(t, a2[p], lg);
                }
            }
        }
        __syncthreads();   // xrs reads done
        if (tid < 256) attbuf[2048 + tid] = lg;
        __syncthreads();
        if (tid < 256) {
            float M = -1e30f;
            float l[8];
            #pragma unroll
            for (int j = 0; j < 8; ++j) {
                l[j] = attbuf[2048 + n * 32 + j * 4 + h];
                M = fmaxf(M, l[j]);
            }
            float S = 0.f;
            #pragma unroll
            for (int j = 0; j < 8; ++j) S += __expf(l[j] - M);
            const float a = __expf(lg - M) / S;
            attbuf[tid] = a;    // alpha1 in [0..255] (xrs dead)
            out[(size_t)NNODES * 256 + (size_t)(bg * NB + n) * 32 + rr * 4 + h] = a;  // betas
        }
    }
    __syncthreads();

    // ---------------- P7: out = relu(alpha1 @ xl1 + bias1) — all reads hoisted ----------------
    {
        const int n  = tid >> 6;          // node 0..7
        const int q  = tid & 63;
        const int c0 = q * 4;
        const int h  = q >> 4;
        f16x4 v[8];
        float a[8];
        #pragma unroll
        for (int r = 0; r < 8; ++r) {
            v[r] = *(const f16x4*)&bufB[swz(n * 8 + r, q >> 1) + (q & 1) * 4];
            a[r] = attbuf[n * 32 + r * 4 + h];
        }
        float o0 = 0.f, o1 = 0.f, o2 = 0.f, o3 = 0.f;
        #pragma unroll
        for (int r = 0; r < 8; ++r) {
            o0 = fmaf((float)v[r][0], a[r], o0);
            o1 = fmaf((float)v[r][1], a[r], o1);
            o2 = fmaf((float)v[r][2], a[r], o2);
            o3 = fmaf((float)v[r][3], a[r], o3);
        }
        float4 res;
        res.x = fmaxf(o0 + bias1[c0 + 0], 0.f);
        res.y = fmaxf(o1 + bias1[c0 + 1], 0.f);
        res.z = fmaxf(o2 + bias1[c0 + 2], 0.f);
        res.w = fmaxf(o3 + bias1[c0 + 3], 0.f);
        *(float4*)&out[(size_t)(bg * NB + n) * 256 + c0] = res;
    }
}

extern "C" void kernel_launch(void* const* d_in, const int* in_sizes, int n_in,
                              void* d_out, int out_size, void* d_ws, size_t ws_size,
                              hipStream_t stream) {
    const float* x     = (const float*)d_in[0];
    const float* Wl0   = (const float*)d_in[1];
    const float* bl0   = (const float*)d_in[2];
    const float* Wr0   = (const float*)d_in[3];
    const float* br0   = (const float*)d_in[4];
    const float* att0  = (const float*)d_in[5];
    const float* bias0 = (const float*)d_in[6];
    const float* Wl1   = (const float*)d_in[7];
    const float* bl1   = (const float*)d_in[8];
    const float* Wr1   = (const float*)d_in[9];
    const float* br1   = (const float*)d_in[10];
    const float* att1  = (const float*)d_in[11];
    const float* bias1 = (const float*)d_in[12];
    _Float16* wt = (_Float16*)d_ws;   // 512 KB
    float* out = (float*)d_out;

    prep_weights<<<64, 256, 0, stream>>>(Wl0, Wr0, Wl1, Wr1, wt);
    gat_fused<<<NNODES / NB, 512, 0, stream>>>(x, bl0, br0, att0, bias0,
                                               bl1, br1, att1, bias1, wt, out);
}